// Round 10
// baseline (417.436 us; speedup 1.0000x reference)
//
#include <hip/hip_runtime.h>
#include <hip/hip_fp16.h>
#include <math.h>

#define IN_C   128
#define HEADS  4
#define F1     128   // HEADS*HID
#define OUT_C  32
#define NEG    0.2f
#define CH1    128   // edge chunk per node-wave (layer 1)
#define CH2    128
#define SH     8     // bucket = dst >> SH (256 dsts per bucket); needs n <= 2^17
#define CHA    8192  // edges per chunk in CSR pass A
#define SCB    4096  // elements per scan block (256 thr x 16)

// ---- fp16 helpers (RNE) ----
__device__ __forceinline__ unsigned short f2h(float f) {
    return __half_as_ushort(__float2half_rn(f));
}
__device__ __forceinline__ float h2f(unsigned short u) {
    return __half2float(__ushort_as_half(u));
}

// ============ CSR pass A1: per-chunk bucket histogram (LDS atomics only) ======
__global__ __launch_bounds__(256) void k_bhist(
    const int* __restrict__ ei, int* __restrict__ bmat, int E_, int n, int NB, int NC)
{
    __shared__ int h[512];
    int t = threadIdx.x, c = blockIdx.x;
    for (int i = t; i < NB; i += 256) h[i] = 0;
    __syncthreads();
    int e0 = c * CHA, e1 = min(e0 + CHA, E_ + n);
    for (int e = e0 + t; e < e1; e += 256) {
        int d = (e < E_) ? ei[E_ + e] : e - E_;
        atomicAdd(&h[d >> SH], 1);
    }
    __syncthreads();
    for (int i = t; i < NB; i += 256) bmat[i * NC + c] = h[i];
}

// ============ CSR pass A2: parallel exclusive scan of bmat (3 stages) ========
__global__ __launch_bounds__(256) void k_scanA(
    int* __restrict__ bmat, int* __restrict__ bsums, int M)
{
    __shared__ int sm[256];
    int t = threadIdx.x;
    int base = blockIdx.x * SCB + t * 16;
    int v[16];
    int s = 0;
    #pragma unroll
    for (int j = 0; j < 16; ++j) {
        int i = base + j;
        v[j] = (i < M) ? bmat[i] : 0;
        s += v[j];
    }
    sm[t] = s;
    __syncthreads();
    for (int off = 1; off < 256; off <<= 1) {
        int a = (t >= off) ? sm[t - off] : 0;
        __syncthreads();
        sm[t] += a;
        __syncthreads();
    }
    int excl = sm[t] - s;
    #pragma unroll
    for (int j = 0; j < 16; ++j) {
        int i = base + j;
        if (i < M) bmat[i] = excl;
        excl += v[j];
    }
    if (t == 255) bsums[blockIdx.x] = sm[255];
}

__global__ __launch_bounds__(256) void k_scanB(int* __restrict__ bsums, int NBLK)
{
    __shared__ int sm[256];
    int t = threadIdx.x;
    int v = (t < NBLK) ? bsums[t] : 0;
    sm[t] = v;
    __syncthreads();
    for (int off = 1; off < 256; off <<= 1) {
        int a = (t >= off) ? sm[t - off] : 0;
        __syncthreads();
        sm[t] += a;
        __syncthreads();
    }
    if (t < NBLK) bsums[t] = sm[t] - v;
}

__global__ __launch_bounds__(256) void k_scanC(
    int* __restrict__ bmat, const int* __restrict__ bsums, int M)
{
    int i = blockIdx.x * 256 + threadIdx.x;
    if (i < M) bmat[i] += bsums[i >> 12];   // 4096 = 1<<12
}

// ============ CSR pass A3: scatter packed recs into (bucket,chunk) ranges =====
__global__ __launch_bounds__(256) void k_bscatter(
    const int* __restrict__ ei, const int* __restrict__ bmat,
    unsigned* __restrict__ recs, int E_, int n, int NB, int NC)
{
    __shared__ int cur[512];
    int t = threadIdx.x, c = blockIdx.x;
    for (int i = t; i < NB; i += 256) cur[i] = bmat[i * NC + c];
    __syncthreads();
    int e0 = c * CHA, e1 = min(e0 + CHA, E_ + n);
    for (int e = e0 + t; e < e1; e += 256) {
        int s, d;
        if (e < E_) { s = ei[e]; d = ei[E_ + e]; } else { s = d = e - E_; }
        int b = d >> SH;
        int p = atomicAdd(&cur[b], 1);   // LDS atomic
        recs[p] = ((unsigned)(d & ((1 << SH) - 1)) << 17) | (unsigned)s;
    }
}

// ============ CSR pass B: per-bucket fine fill (one block owns one bucket) ====
__global__ __launch_bounds__(256) void k_bfill(
    const unsigned* __restrict__ recs, const int* __restrict__ bmat,
    int* __restrict__ row_off, int* __restrict__ csr, int n, int NB, int NC, int EE)
{
    __shared__ int deg[256];
    __shared__ int cur[256];
    int t = threadIdx.x, b = blockIdx.x;
    int r0 = bmat[b * NC];
    int r1 = (b + 1 < NB) ? bmat[(b + 1) * NC] : EE;
    deg[t] = 0;
    __syncthreads();
    for (int i = r0 + t; i < r1; i += 256)
        atomicAdd(&deg[recs[i] >> 17], 1);
    __syncthreads();
    int v = deg[t];
    for (int off = 1; off < 256; off <<= 1) {
        int a = (t >= off) ? deg[t - off] : 0;
        __syncthreads();
        deg[t] += a;
        __syncthreads();
    }
    int excl = deg[t] - v;
    int dst = (b << SH) + t;
    if (dst < n) row_off[dst] = r0 + excl;
    cur[t] = excl;
    if (b == NB - 1 && t == 0) row_off[n] = EE;
    __syncthreads();
    for (int i = r0 + t; i < r1; i += 256) {
        unsigned rec = recs[i];
        int dl = rec >> 17;
        int p = atomicAdd(&cur[dl], 1);   // LDS atomic
        csr[r0 + p] = (int)(rec & 0x1FFFFu);
    }
}

// ============ layer-1 GEMM: h1 = x@W1 (fp16 out) + fused att reduction =======
#define XS_STRIDE 68
__global__ __launch_bounds__(256) void k_gemm1(
    const float* __restrict__ x, const float* __restrict__ W,
    const float* __restrict__ as_w, const float* __restrict__ ad_w,
    unsigned short* __restrict__ h1h, float* __restrict__ as1,
    float* __restrict__ ad1, int n)
{
    __shared__ float Ws[128 * 64];
    __shared__ float xs[128 * XS_STRIDE];
    int t = threadIdx.x;
    int half = blockIdx.x & 1;
    int n0 = (blockIdx.x >> 1) * 64;

    for (int i = t; i < 128 * 16; i += 256) {
        int k = i >> 4, c4 = (i & 15) * 4;
        *(float4*)&Ws[k * 64 + c4] = *(const float4*)&W[k * 128 + half * 64 + c4];
    }
    for (int i = t; i < 64 * 32; i += 256) {
        int nl = i & 63, k4 = (i >> 6) * 4;
        int nn = n0 + nl;
        float4 v = (nn < n) ? *(const float4*)&x[(size_t)nn * 128 + k4]
                            : make_float4(0.f, 0.f, 0.f, 0.f);
        xs[(k4 + 0) * XS_STRIDE + nl] = v.x;
        xs[(k4 + 1) * XS_STRIDE + nl] = v.y;
        xs[(k4 + 2) * XS_STRIDE + nl] = v.z;
        xs[(k4 + 3) * XS_STRIDE + nl] = v.w;
    }
    __syncthreads();

    int tx = t & 15, ty = t >> 4;
    float acc[4][4] = {};
    #pragma unroll 8
    for (int k = 0; k < 128; ++k) {
        float4 a = *(float4*)&xs[k * XS_STRIDE + ty * 4];
        float4 b = *(float4*)&Ws[k * 64 + tx * 4];
        float av[4] = {a.x, a.y, a.z, a.w};
        float bv[4] = {b.x, b.y, b.z, b.w};
        #pragma unroll
        for (int i = 0; i < 4; ++i)
            #pragma unroll
            for (int j = 0; j < 4; ++j)
                acc[i][j] = fmaf(av[i], bv[j], acc[i][j]);
    }
    int cbase = half * 64 + tx * 4;
    float4 aws = *(const float4*)&as_w[cbase];
    float4 awd = *(const float4*)&ad_w[cbase];
    float sa[4], sd[4];
    #pragma unroll
    for (int i = 0; i < 4; ++i) {
        int nn = n0 + ty * 4 + i;
        sa[i] = acc[i][0]*aws.x + acc[i][1]*aws.y + acc[i][2]*aws.z + acc[i][3]*aws.w;
        sd[i] = acc[i][0]*awd.x + acc[i][1]*awd.y + acc[i][2]*awd.z + acc[i][3]*awd.w;
        if (nn < n) {
            ushort4 p;
            p.x = f2h(acc[i][0]); p.y = f2h(acc[i][1]);
            p.z = f2h(acc[i][2]); p.w = f2h(acc[i][3]);
            *(ushort4*)&h1h[(size_t)nn * 128 + cbase] = p;
        }
    }
    #pragma unroll
    for (int o = 1; o < 8; o <<= 1) {
        #pragma unroll
        for (int i = 0; i < 4; ++i) {
            sa[i] += __shfl_xor(sa[i], o);
            sd[i] += __shfl_xor(sd[i], o);
        }
    }
    if ((tx & 7) == 0) {
        int head = half * 2 + (tx >> 3);
        #pragma unroll
        for (int i = 0; i < 4; ++i) {
            int nn = n0 + ty * 4 + i;
            if (nn < n) {
                as1[(size_t)nn * 4 + head] = sa[i];
                ad1[(size_t)nn * 4 + head] = sd[i];
            }
        }
    }
}

// ============ layer-2 GEMM: h2 = z@W2 (fp16 out) + fused att reduction =======
#define ZS_STRIDE 66
__global__ __launch_bounds__(256) void k_gemm2(
    const float* __restrict__ z, const float* __restrict__ W,
    const float* __restrict__ as_w, const float* __restrict__ ad_w,
    unsigned short* __restrict__ h2h, float* __restrict__ as2,
    float* __restrict__ ad2, int n)
{
    __shared__ float Ws[128 * 32];
    __shared__ float zs[128 * ZS_STRIDE];
    int t = threadIdx.x;
    int n0 = blockIdx.x * 64;

    for (int i = t; i < 128 * 8; i += 256) {
        int k = i >> 3, c4 = (i & 7) * 4;
        *(float4*)&Ws[k * 32 + c4] = *(const float4*)&W[k * 32 + c4];
    }
    for (int i = t; i < 64 * 32; i += 256) {
        int nl = i & 63, k4 = (i >> 6) * 4;
        int nn = n0 + nl;
        float4 v = (nn < n) ? *(const float4*)&z[(size_t)nn * 128 + k4]
                            : make_float4(0.f, 0.f, 0.f, 0.f);
        zs[(k4 + 0) * ZS_STRIDE + nl] = v.x;
        zs[(k4 + 1) * ZS_STRIDE + nl] = v.y;
        zs[(k4 + 2) * ZS_STRIDE + nl] = v.z;
        zs[(k4 + 3) * ZS_STRIDE + nl] = v.w;
    }
    __syncthreads();

    int tx = t & 7, ty = t >> 3;
    float acc[2][4] = {};
    #pragma unroll 8
    for (int k = 0; k < 128; ++k) {
        float2 a = *(float2*)&zs[k * ZS_STRIDE + ty * 2];
        float4 b = *(float4*)&Ws[k * 32 + tx * 4];
        float av[2] = {a.x, a.y};
        float bv[4] = {b.x, b.y, b.z, b.w};
        #pragma unroll
        for (int i = 0; i < 2; ++i)
            #pragma unroll
            for (int j = 0; j < 4; ++j)
                acc[i][j] = fmaf(av[i], bv[j], acc[i][j]);
    }
    float4 aws = *(const float4*)&as_w[tx * 4];
    float4 awd = *(const float4*)&ad_w[tx * 4];
    float sa[2], sd[2];
    #pragma unroll
    for (int i = 0; i < 2; ++i) {
        int nn = n0 + ty * 2 + i;
        sa[i] = acc[i][0]*aws.x + acc[i][1]*aws.y + acc[i][2]*aws.z + acc[i][3]*aws.w;
        sd[i] = acc[i][0]*awd.x + acc[i][1]*awd.y + acc[i][2]*awd.z + acc[i][3]*awd.w;
        if (nn < n) {
            ushort4 p;
            p.x = f2h(acc[i][0]); p.y = f2h(acc[i][1]);
            p.z = f2h(acc[i][2]); p.w = f2h(acc[i][3]);
            *(ushort4*)&h2h[(size_t)nn * 32 + tx * 4] = p;
        }
    }
    #pragma unroll
    for (int o = 1; o < 8; o <<= 1) {
        #pragma unroll
        for (int i = 0; i < 2; ++i) {
            sa[i] += __shfl_xor(sa[i], o);
            sd[i] += __shfl_xor(sd[i], o);
        }
    }
    if (tx == 0) {
        #pragma unroll
        for (int i = 0; i < 2; ++i) {
            int nn = n0 + ty * 2 + i;
            if (nn < n) { as2[nn] = sa[i]; ad2[nn] = sd[i]; }
        }
    }
}

// ============ fused layer-1 GAT: softmax + fp16 gather + ELU ============
// one wave per dst node. Score phase: lanes cover edges {lane, lane+64};
// probs in round-7's interleaved layout sp[j*4+h] (float4 write/lane —
// measured conflict-free). Gather: 2 edges/iter (eo=lane>>5), lane covers
// 4 ch via ushort4 (8B); sp reads hit 8 distinct banks (broadcast, free).
__global__ __launch_bounds__(256) void k_gat1(
    const int* __restrict__ row_off, const int* __restrict__ csr,
    const float* __restrict__ as1, const float* __restrict__ ad1,
    const unsigned short* __restrict__ h1h, const float* __restrict__ b1,
    float* __restrict__ z, int n)
{
    int w = threadIdx.x >> 6, lane = threadIdx.x & 63;
    int node = blockIdx.x * 4 + w;
    if (node >= n) return;
    __shared__ int   s_src_all[4][CH1];       // 2 KB
    __shared__ float s_p_all[4][CH1 * 4];     // 8 KB, sp[j*4+h]
    int* ssrc = s_src_all[w];
    float* sp = s_p_all[w];

    float add0 = ad1[(size_t)node * 4 + 0];
    float add1 = ad1[(size_t)node * 4 + 1];
    float add2 = ad1[(size_t)node * 4 + 2];
    float add3 = ad1[(size_t)node * 4 + 3];
    int beg = row_off[node], end = row_off[node + 1];
    int eo = lane >> 5;        // edge parity in gather phase
    int cl = lane & 31;        // channel group: 4*cl .. 4*cl+3
    int h  = cl >> 3;          // my head in gather phase

    float mr0 = -1e30f, mr1 = -1e30f, mr2 = -1e30f, mr3 = -1e30f;
    float sr0 = 0.f, sr1 = 0.f, sr2 = 0.f, sr3 = 0.f;
    float acc0 = 0.f, acc1 = 0.f, acc2 = 0.f, acc3 = 0.f;

    for (int c = beg; c < end; c += CH1) {
        int cnt = min(CH1, end - c);
        int sA = 0, sB = 0;
        float scA0=-1e30f, scA1=-1e30f, scA2=-1e30f, scA3=-1e30f;
        float scB0=-1e30f, scB1=-1e30f, scB2=-1e30f, scB3=-1e30f;
        bool hasA = lane < cnt, hasB = lane + 64 < cnt;
        if (hasA) {
            sA = csr[c + lane];
            ssrc[lane] = sA;
            float4 av = *(const float4*)&as1[(size_t)sA * 4];
            float v;
            v = av.x + add0; scA0 = v > 0.f ? v : NEG * v;
            v = av.y + add1; scA1 = v > 0.f ? v : NEG * v;
            v = av.z + add2; scA2 = v > 0.f ? v : NEG * v;
            v = av.w + add3; scA3 = v > 0.f ? v : NEG * v;
        }
        if (hasB) {
            sB = csr[c + lane + 64];
            ssrc[lane + 64] = sB;
            float4 av = *(const float4*)&as1[(size_t)sB * 4];
            float v;
            v = av.x + add0; scB0 = v > 0.f ? v : NEG * v;
            v = av.y + add1; scB1 = v > 0.f ? v : NEG * v;
            v = av.z + add2; scB2 = v > 0.f ? v : NEG * v;
            v = av.w + add3; scB3 = v > 0.f ? v : NEG * v;
        }
        float lm0 = fmaxf(scA0, scB0), lm1 = fmaxf(scA1, scB1);
        float lm2 = fmaxf(scA2, scB2), lm3 = fmaxf(scA3, scB3);
        #pragma unroll
        for (int o = 32; o; o >>= 1) {
            lm0 = fmaxf(lm0, __shfl_xor(lm0, o));
            lm1 = fmaxf(lm1, __shfl_xor(lm1, o));
            lm2 = fmaxf(lm2, __shfl_xor(lm2, o));
            lm3 = fmaxf(lm3, __shfl_xor(lm3, o));
        }
        float nm0 = fmaxf(mr0, lm0), nm1 = fmaxf(mr1, lm1);
        float nm2 = fmaxf(mr2, lm2), nm3 = fmaxf(mr3, lm3);
        float om  = h == 0 ? mr0 : h == 1 ? mr1 : h == 2 ? mr2 : mr3;
        float nmh = h == 0 ? nm0 : h == 1 ? nm1 : h == 2 ? nm2 : nm3;
        float r = __expf(om - nmh);
        acc0 *= r; acc1 *= r; acc2 *= r; acc3 *= r;
        float ls0 = 0.f, ls1 = 0.f, ls2 = 0.f, ls3 = 0.f;
        if (hasA) {
            float p0 = __expf(scA0 - nm0), p1 = __expf(scA1 - nm1);
            float p2 = __expf(scA2 - nm2), p3 = __expf(scA3 - nm3);
            *(float4*)&sp[lane * 4] = make_float4(p0, p1, p2, p3);
            ls0 += p0; ls1 += p1; ls2 += p2; ls3 += p3;
        }
        if (hasB) {
            float p0 = __expf(scB0 - nm0), p1 = __expf(scB1 - nm1);
            float p2 = __expf(scB2 - nm2), p3 = __expf(scB3 - nm3);
            *(float4*)&sp[(lane + 64) * 4] = make_float4(p0, p1, p2, p3);
            ls0 += p0; ls1 += p1; ls2 += p2; ls3 += p3;
        }
        #pragma unroll
        for (int o = 32; o; o >>= 1) {
            ls0 += __shfl_xor(ls0, o);
            ls1 += __shfl_xor(ls1, o);
            ls2 += __shfl_xor(ls2, o);
            ls3 += __shfl_xor(ls3, o);
        }
        sr0 = sr0 * __expf(mr0 - nm0) + ls0;
        sr1 = sr1 * __expf(mr1 - nm1) + ls1;
        sr2 = sr2 * __expf(mr2 - nm2) + ls2;
        sr3 = sr3 * __expf(mr3 - nm3) + ls3;
        __threadfence_block();
        // ---- gather: 2 edges/iter; sp[j*4+h] reads hit distinct banks ----
        #pragma unroll 2
        for (int jj = 0; jj < cnt; jj += 2) {
            int j = jj + eo;
            if (j < cnt) {
                int src = ssrc[j];
                float p = sp[j * 4 + h];
                ushort4 u = *(const ushort4*)&h1h[(size_t)src * 128 + 4 * cl];
                acc0 = fmaf(p, h2f(u.x), acc0);
                acc1 = fmaf(p, h2f(u.y), acc1);
                acc2 = fmaf(p, h2f(u.z), acc2);
                acc3 = fmaf(p, h2f(u.w), acc3);
            }
        }
        mr0 = nm0; mr1 = nm1; mr2 = nm2; mr3 = nm3;
    }
    // fold the two edge-parity halves
    acc0 += __shfl_xor(acc0, 32);
    acc1 += __shfl_xor(acc1, 32);
    acc2 += __shfl_xor(acc2, 32);
    acc3 += __shfl_xor(acc3, 32);
    float srh = h == 0 ? sr0 : h == 1 ? sr1 : h == 2 ? sr2 : sr3;
    float4 bb = *(const float4*)&b1[4 * cl];
    float v0 = acc0 / srh + bb.x;
    float v1 = acc1 / srh + bb.y;
    float v2 = acc2 / srh + bb.z;
    float v3 = acc3 / srh + bb.w;
    v0 = v0 > 0.f ? v0 : (__expf(v0) - 1.f);
    v1 = v1 > 0.f ? v1 : (__expf(v1) - 1.f);
    v2 = v2 > 0.f ? v2 : (__expf(v2) - 1.f);
    v3 = v3 > 0.f ? v3 : (__expf(v3) - 1.f);
    if (lane < 32)
        *(float4*)&z[(size_t)node * F1 + 4 * cl] = make_float4(v0, v1, v2, v3);
}

// ============ fused layer-2 GAT + log_softmax (fp16 gather) ============
// rec={src,p} uint2 at stride-2 (2-way aliasing = free); 4 edges in flight.
__global__ __launch_bounds__(256) void k_gat2(
    const int* __restrict__ row_off, const int* __restrict__ csr,
    const float* __restrict__ as2, const float* __restrict__ ad2,
    const unsigned short* __restrict__ h2h, const float* __restrict__ b2,
    float* __restrict__ y, int n)
{
    int w = threadIdx.x >> 6, lane = threadIdx.x & 63;
    int node = blockIdx.x * 4 + w;
    if (node >= n) return;
    __shared__ unsigned s_rec_all[4][CH2 * 2];   // 4 KB
    unsigned* rec = s_rec_all[w];

    float addv = ad2[node];
    int beg = row_off[node], end = row_off[node + 1];
    int c2 = lane & 15, eo = lane >> 4;   // 4 edges in flight
    float mr = -1e30f, sr = 0.f, acc0 = 0.f, acc1 = 0.f;

    for (int c = beg; c < end; c += CH2) {
        int cnt = min(CH2, end - c);
        int sA = 0, sB = 0;
        float scA = -1e30f, scB = -1e30f;
        bool hasA = lane < cnt, hasB = lane + 64 < cnt;
        if (hasA) {
            sA = csr[c + lane];
            float v = as2[sA] + addv;
            scA = v > 0.f ? v : NEG * v;
        }
        if (hasB) {
            sB = csr[c + lane + 64];
            float v = as2[sB] + addv;
            scB = v > 0.f ? v : NEG * v;
        }
        float lm = fmaxf(scA, scB);
        #pragma unroll
        for (int o = 32; o; o >>= 1) lm = fmaxf(lm, __shfl_xor(lm, o));
        float nm = fmaxf(mr, lm);
        float r = __expf(mr - nm);
        acc0 *= r; acc1 *= r; sr *= r;
        float ls = 0.f;
        if (hasA) {
            float p = __expf(scA - nm);
            uint2 rr; rr.x = (unsigned)sA; rr.y = __float_as_uint(p);
            *(uint2*)&rec[lane * 2] = rr;
            ls += p;
        }
        if (hasB) {
            float p = __expf(scB - nm);
            uint2 rr; rr.x = (unsigned)sB; rr.y = __float_as_uint(p);
            *(uint2*)&rec[(lane + 64) * 2] = rr;
            ls += p;
        }
        #pragma unroll
        for (int o = 32; o; o >>= 1) ls += __shfl_xor(ls, o);
        sr += ls;
        __threadfence_block();
        #pragma unroll 4
        for (int jj = 0; jj < cnt; jj += 4) {
            int j = jj + eo;
            if (j < cnt) {
                uint2 rr = *(uint2*)&rec[j * 2];
                float p = __uint_as_float(rr.y);
                ushort2 u = *(const ushort2*)&h2h[(size_t)rr.x * 32 + 2 * c2];
                acc0 = fmaf(p, h2f(u.x), acc0);
                acc1 = fmaf(p, h2f(u.y), acc1);
            }
        }
        mr = nm;
    }
    acc0 += __shfl_xor(acc0, 16); acc0 += __shfl_xor(acc0, 32);
    acc1 += __shfl_xor(acc1, 16); acc1 += __shfl_xor(acc1, 32);
    float v0 = acc0 / sr + b2[2 * c2];
    float v1 = acc1 / sr + b2[2 * c2 + 1];
    float m = fmaxf(v0, v1);
    #pragma unroll
    for (int o = 8; o; o >>= 1) m = fmaxf(m, __shfl_xor(m, o));
    float ss = __expf(v0 - m) + __expf(v1 - m);
    #pragma unroll
    for (int o = 8; o; o >>= 1) ss += __shfl_xor(ss, o);
    float lg = m + logf(ss);
    if (lane < 16)
        *(float2*)&y[(size_t)node * OUT_C + 2 * c2] = make_float2(v0 - lg, v1 - lg);
}

extern "C" void kernel_launch(void* const* d_in, const int* in_sizes, int n_in,
                              void* d_out, int out_size, void* d_ws, size_t ws_size,
                              hipStream_t stream) {
    const float* x    = (const float*)d_in[0];
    const int*   ei   = (const int*)d_in[1];
    const float* W1   = (const float*)d_in[2];
    const float* as1w = (const float*)d_in[3];
    const float* ad1w = (const float*)d_in[4];
    const float* b1   = (const float*)d_in[5];
    const float* W2   = (const float*)d_in[6];
    const float* as2w = (const float*)d_in[7];
    const float* ad2w = (const float*)d_in[8];
    const float* b2   = (const float*)d_in[9];
    float* out = (float*)d_out;

    int n  = in_sizes[0] / IN_C;
    int E_ = in_sizes[1] / 2;
    int EE = E_ + n;

    int NB = (n + (1 << SH) - 1) >> SH;        // buckets (<=512 for n<=131072)
    int NC = (EE + CHA - 1) / CHA;             // chunks
    int M  = NB * NC;
    int NBLK = (M + SCB - 1) / SCB;            // scan blocks (<=256)

    char* w = (char*)d_ws;
    size_t off = 0;
    auto take = [&](size_t elems) { void* p = w + off; off += ((elems * 4 + 255) & ~(size_t)255); return p; };
    int* bmat      = (int*)take((size_t)M);
    int* bsums     = (int*)take(256);
    unsigned* recs = (unsigned*)take((size_t)EE);
    int* row_off   = (int*)take((size_t)n + 1);
    int* csr       = (int*)take((size_t)EE);
    float* as1     = (float*)take((size_t)n * 4);
    float* ad1     = (float*)take((size_t)n * 4);
    unsigned short* h1h = (unsigned short*)take((size_t)n * 64);  // n*128 fp16
    float* z       = (float*)take((size_t)n * 128);
    unsigned short* h2h = (unsigned short*)take((size_t)n * 16);  // n*32 fp16
    float* as2     = (float*)take((size_t)n);
    float* ad2     = (float*)take((size_t)n);

    // CSR build: bucketed counting sort, no global atomics, parallel scan
    k_bhist   <<<NC, 256, 0, stream>>>(ei, bmat, E_, n, NB, NC);
    k_scanA   <<<NBLK, 256, 0, stream>>>(bmat, bsums, M);
    k_scanB   <<<1, 256, 0, stream>>>(bsums, NBLK);
    k_scanC   <<<(M + 255) / 256, 256, 0, stream>>>(bmat, bsums, M);
    k_bscatter<<<NC, 256, 0, stream>>>(ei, bmat, recs, E_, n, NB, NC);
    k_bfill   <<<NB, 256, 0, stream>>>(recs, bmat, row_off, csr, n, NB, NC, EE);

    // layer 1
    int nt = (n + 63) / 64;
    k_gemm1<<<nt * 2, 256, 0, stream>>>(x, W1, as1w, ad1w, h1h, as1, ad1, n);
    int gG = (n + 3) / 4;
    k_gat1<<<gG, 256, 0, stream>>>(row_off, csr, as1, ad1, h1h, b1, z, n);

    // layer 2
    k_gemm2<<<nt, 256, 0, stream>>>(z, W2, as2w, ad2w, h2h, as2, ad2, n);
    k_gat2<<<gG, 256, 0, stream>>>(row_off, csr, as2, ad2, h2h, b2, out, n);
}

// Round 11
// 400.973 us; speedup vs baseline: 1.0411x; 1.0411x over previous
//
#include <hip/hip_runtime.h>
#include <hip/hip_fp16.h>
#include <math.h>

#define IN_C   128
#define HEADS  4
#define F1     128   // HEADS*HID
#define OUT_C  32
#define NEG    0.2f
#define CH1    128   // edge chunk per node-wave (layer 1)
#define CH2    128
#define SH     8     // bucket = dst >> SH (256 dsts per bucket); needs n <= 2^17
#define CHA    8192  // edges per chunk in CSR pass A
#define SCB    4096  // elements per scan block (256 thr x 16)

// ---- fp16 helpers (RNE) ----
__device__ __forceinline__ unsigned short f2h(float f) {
    return __half_as_ushort(__float2half_rn(f));
}
__device__ __forceinline__ float h2f(unsigned short u) {
    return __half2float(__ushort_as_half(u));
}

// ============ CSR pass A1: per-chunk bucket histogram (LDS atomics only) ======
__global__ __launch_bounds__(256) void k_bhist(
    const int* __restrict__ ei, int* __restrict__ bmat, int E_, int n, int NB, int NC)
{
    __shared__ int h[512];
    int t = threadIdx.x, c = blockIdx.x;
    for (int i = t; i < NB; i += 256) h[i] = 0;
    __syncthreads();
    int e0 = c * CHA, e1 = min(e0 + CHA, E_ + n);
    for (int e = e0 + t; e < e1; e += 256) {
        int d = (e < E_) ? ei[E_ + e] : e - E_;
        atomicAdd(&h[d >> SH], 1);
    }
    __syncthreads();
    for (int i = t; i < NB; i += 256) bmat[i * NC + c] = h[i];
}

// ============ CSR pass A2: parallel exclusive scan of bmat (3 stages) ========
__global__ __launch_bounds__(256) void k_scanA(
    int* __restrict__ bmat, int* __restrict__ bsums, int M)
{
    __shared__ int sm[256];
    int t = threadIdx.x;
    int base = blockIdx.x * SCB + t * 16;
    int v[16];
    int s = 0;
    #pragma unroll
    for (int j = 0; j < 16; ++j) {
        int i = base + j;
        v[j] = (i < M) ? bmat[i] : 0;
        s += v[j];
    }
    sm[t] = s;
    __syncthreads();
    for (int off = 1; off < 256; off <<= 1) {
        int a = (t >= off) ? sm[t - off] : 0;
        __syncthreads();
        sm[t] += a;
        __syncthreads();
    }
    int excl = sm[t] - s;
    #pragma unroll
    for (int j = 0; j < 16; ++j) {
        int i = base + j;
        if (i < M) bmat[i] = excl;
        excl += v[j];
    }
    if (t == 255) bsums[blockIdx.x] = sm[255];
}

__global__ __launch_bounds__(256) void k_scanB(int* __restrict__ bsums, int NBLK)
{
    __shared__ int sm[256];
    int t = threadIdx.x;
    int v = (t < NBLK) ? bsums[t] : 0;
    sm[t] = v;
    __syncthreads();
    for (int off = 1; off < 256; off <<= 1) {
        int a = (t >= off) ? sm[t - off] : 0;
        __syncthreads();
        sm[t] += a;
        __syncthreads();
    }
    if (t < NBLK) bsums[t] = sm[t] - v;
}

__global__ __launch_bounds__(256) void k_scanC(
    int* __restrict__ bmat, const int* __restrict__ bsums, int M)
{
    int i = blockIdx.x * 256 + threadIdx.x;
    if (i < M) bmat[i] += bsums[i >> 12];   // 4096 = 1<<12
}

// ============ CSR pass A3: scatter packed recs into (bucket,chunk) ranges =====
__global__ __launch_bounds__(256) void k_bscatter(
    const int* __restrict__ ei, const int* __restrict__ bmat,
    unsigned* __restrict__ recs, int E_, int n, int NB, int NC)
{
    __shared__ int cur[512];
    int t = threadIdx.x, c = blockIdx.x;
    for (int i = t; i < NB; i += 256) cur[i] = bmat[i * NC + c];
    __syncthreads();
    int e0 = c * CHA, e1 = min(e0 + CHA, E_ + n);
    for (int e = e0 + t; e < e1; e += 256) {
        int s, d;
        if (e < E_) { s = ei[e]; d = ei[E_ + e]; } else { s = d = e - E_; }
        int b = d >> SH;
        int p = atomicAdd(&cur[b], 1);   // LDS atomic
        recs[p] = ((unsigned)(d & ((1 << SH) - 1)) << 17) | (unsigned)s;
    }
}

// ============ CSR pass B: per-bucket fine fill (one block owns one bucket) ====
__global__ __launch_bounds__(256) void k_bfill(
    const unsigned* __restrict__ recs, const int* __restrict__ bmat,
    int* __restrict__ row_off, int* __restrict__ csr, int n, int NB, int NC, int EE)
{
    __shared__ int deg[256];
    __shared__ int cur[256];
    int t = threadIdx.x, b = blockIdx.x;
    int r0 = bmat[b * NC];
    int r1 = (b + 1 < NB) ? bmat[(b + 1) * NC] : EE;
    deg[t] = 0;
    __syncthreads();
    for (int i = r0 + t; i < r1; i += 256)
        atomicAdd(&deg[recs[i] >> 17], 1);
    __syncthreads();
    int v = deg[t];
    for (int off = 1; off < 256; off <<= 1) {
        int a = (t >= off) ? deg[t - off] : 0;
        __syncthreads();
        deg[t] += a;
        __syncthreads();
    }
    int excl = deg[t] - v;
    int dst = (b << SH) + t;
    if (dst < n) row_off[dst] = r0 + excl;
    cur[t] = excl;
    if (b == NB - 1 && t == 0) row_off[n] = EE;
    __syncthreads();
    for (int i = r0 + t; i < r1; i += 256) {
        unsigned rec = recs[i];
        int dl = rec >> 17;
        int p = atomicAdd(&cur[dl], 1);   // LDS atomic
        csr[r0 + p] = (int)(rec & 0x1FFFFu);
    }
}

// ============ layer-1 GEMM: h1 = x@W1 (fp16 out) + fused att reduction =======
#define XS_STRIDE 68
__global__ __launch_bounds__(256) void k_gemm1(
    const float* __restrict__ x, const float* __restrict__ W,
    const float* __restrict__ as_w, const float* __restrict__ ad_w,
    unsigned short* __restrict__ h1h, float* __restrict__ as1,
    float* __restrict__ ad1, int n)
{
    __shared__ float Ws[128 * 64];
    __shared__ float xs[128 * XS_STRIDE];
    int t = threadIdx.x;
    int half = blockIdx.x & 1;
    int n0 = (blockIdx.x >> 1) * 64;

    for (int i = t; i < 128 * 16; i += 256) {
        int k = i >> 4, c4 = (i & 15) * 4;
        *(float4*)&Ws[k * 64 + c4] = *(const float4*)&W[k * 128 + half * 64 + c4];
    }
    for (int i = t; i < 64 * 32; i += 256) {
        int nl = i & 63, k4 = (i >> 6) * 4;
        int nn = n0 + nl;
        float4 v = (nn < n) ? *(const float4*)&x[(size_t)nn * 128 + k4]
                            : make_float4(0.f, 0.f, 0.f, 0.f);
        xs[(k4 + 0) * XS_STRIDE + nl] = v.x;
        xs[(k4 + 1) * XS_STRIDE + nl] = v.y;
        xs[(k4 + 2) * XS_STRIDE + nl] = v.z;
        xs[(k4 + 3) * XS_STRIDE + nl] = v.w;
    }
    __syncthreads();

    int tx = t & 15, ty = t >> 4;
    float acc[4][4] = {};
    #pragma unroll 8
    for (int k = 0; k < 128; ++k) {
        float4 a = *(float4*)&xs[k * XS_STRIDE + ty * 4];
        float4 b = *(float4*)&Ws[k * 64 + tx * 4];
        float av[4] = {a.x, a.y, a.z, a.w};
        float bv[4] = {b.x, b.y, b.z, b.w};
        #pragma unroll
        for (int i = 0; i < 4; ++i)
            #pragma unroll
            for (int j = 0; j < 4; ++j)
                acc[i][j] = fmaf(av[i], bv[j], acc[i][j]);
    }
    int cbase = half * 64 + tx * 4;
    float4 aws = *(const float4*)&as_w[cbase];
    float4 awd = *(const float4*)&ad_w[cbase];
    float sa[4], sd[4];
    #pragma unroll
    for (int i = 0; i < 4; ++i) {
        int nn = n0 + ty * 4 + i;
        sa[i] = acc[i][0]*aws.x + acc[i][1]*aws.y + acc[i][2]*aws.z + acc[i][3]*aws.w;
        sd[i] = acc[i][0]*awd.x + acc[i][1]*awd.y + acc[i][2]*awd.z + acc[i][3]*awd.w;
        if (nn < n) {
            ushort4 p;
            p.x = f2h(acc[i][0]); p.y = f2h(acc[i][1]);
            p.z = f2h(acc[i][2]); p.w = f2h(acc[i][3]);
            *(ushort4*)&h1h[(size_t)nn * 128 + cbase] = p;
        }
    }
    #pragma unroll
    for (int o = 1; o < 8; o <<= 1) {
        #pragma unroll
        for (int i = 0; i < 4; ++i) {
            sa[i] += __shfl_xor(sa[i], o);
            sd[i] += __shfl_xor(sd[i], o);
        }
    }
    if ((tx & 7) == 0) {
        int head = half * 2 + (tx >> 3);
        #pragma unroll
        for (int i = 0; i < 4; ++i) {
            int nn = n0 + ty * 4 + i;
            if (nn < n) {
                as1[(size_t)nn * 4 + head] = sa[i];
                ad1[(size_t)nn * 4 + head] = sd[i];
            }
        }
    }
}

// ============ layer-2 GEMM: h2 = z@W2 (fp16 out) + fused att reduction =======
#define ZS_STRIDE 66
__global__ __launch_bounds__(256) void k_gemm2(
    const float* __restrict__ z, const float* __restrict__ W,
    const float* __restrict__ as_w, const float* __restrict__ ad_w,
    unsigned short* __restrict__ h2h, float* __restrict__ as2,
    float* __restrict__ ad2, int n)
{
    __shared__ float Ws[128 * 32];
    __shared__ float zs[128 * ZS_STRIDE];
    int t = threadIdx.x;
    int n0 = blockIdx.x * 64;

    for (int i = t; i < 128 * 8; i += 256) {
        int k = i >> 3, c4 = (i & 7) * 4;
        *(float4*)&Ws[k * 32 + c4] = *(const float4*)&W[k * 32 + c4];
    }
    for (int i = t; i < 64 * 32; i += 256) {
        int nl = i & 63, k4 = (i >> 6) * 4;
        int nn = n0 + nl;
        float4 v = (nn < n) ? *(const float4*)&z[(size_t)nn * 128 + k4]
                            : make_float4(0.f, 0.f, 0.f, 0.f);
        zs[(k4 + 0) * ZS_STRIDE + nl] = v.x;
        zs[(k4 + 1) * ZS_STRIDE + nl] = v.y;
        zs[(k4 + 2) * ZS_STRIDE + nl] = v.z;
        zs[(k4 + 3) * ZS_STRIDE + nl] = v.w;
    }
    __syncthreads();

    int tx = t & 7, ty = t >> 3;
    float acc[2][4] = {};
    #pragma unroll 8
    for (int k = 0; k < 128; ++k) {
        float2 a = *(float2*)&zs[k * ZS_STRIDE + ty * 2];
        float4 b = *(float4*)&Ws[k * 32 + tx * 4];
        float av[2] = {a.x, a.y};
        float bv[4] = {b.x, b.y, b.z, b.w};
        #pragma unroll
        for (int i = 0; i < 2; ++i)
            #pragma unroll
            for (int j = 0; j < 4; ++j)
                acc[i][j] = fmaf(av[i], bv[j], acc[i][j]);
    }
    float4 aws = *(const float4*)&as_w[tx * 4];
    float4 awd = *(const float4*)&ad_w[tx * 4];
    float sa[2], sd[2];
    #pragma unroll
    for (int i = 0; i < 2; ++i) {
        int nn = n0 + ty * 2 + i;
        sa[i] = acc[i][0]*aws.x + acc[i][1]*aws.y + acc[i][2]*aws.z + acc[i][3]*aws.w;
        sd[i] = acc[i][0]*awd.x + acc[i][1]*awd.y + acc[i][2]*awd.z + acc[i][3]*awd.w;
        if (nn < n) {
            ushort4 p;
            p.x = f2h(acc[i][0]); p.y = f2h(acc[i][1]);
            p.z = f2h(acc[i][2]); p.w = f2h(acc[i][3]);
            *(ushort4*)&h2h[(size_t)nn * 32 + tx * 4] = p;
        }
    }
    #pragma unroll
    for (int o = 1; o < 8; o <<= 1) {
        #pragma unroll
        for (int i = 0; i < 2; ++i) {
            sa[i] += __shfl_xor(sa[i], o);
            sd[i] += __shfl_xor(sd[i], o);
        }
    }
    if (tx == 0) {
        #pragma unroll
        for (int i = 0; i < 2; ++i) {
            int nn = n0 + ty * 2 + i;
            if (nn < n) { as2[nn] = sa[i]; ad2[nn] = sd[i]; }
        }
    }
}

// ============ fused layer-1 GAT: softmax + fp16 gather + ELU ============
// one wave per dst node. Score phase: lanes cover edges {lane, lane+64};
// probs interleaved sp[j*4+h] (conflict-free, round-7-verified).
// Gather: main loop 8 edges/block (4 per half-wave, 4 independent global
// loads issued back-to-back -> 4-deep MLP), guarded tail for the rest.
__global__ __launch_bounds__(256) void k_gat1(
    const int* __restrict__ row_off, const int* __restrict__ csr,
    const float* __restrict__ as1, const float* __restrict__ ad1,
    const unsigned short* __restrict__ h1h, const float* __restrict__ b1,
    float* __restrict__ z, int n)
{
    int w = threadIdx.x >> 6, lane = threadIdx.x & 63;
    int node = blockIdx.x * 4 + w;
    if (node >= n) return;
    __shared__ int   s_src_all[4][CH1];       // 2 KB
    __shared__ float s_p_all[4][CH1 * 4];     // 8 KB, sp[j*4+h]
    int* ssrc = s_src_all[w];
    float* sp = s_p_all[w];

    float add0 = ad1[(size_t)node * 4 + 0];
    float add1 = ad1[(size_t)node * 4 + 1];
    float add2 = ad1[(size_t)node * 4 + 2];
    float add3 = ad1[(size_t)node * 4 + 3];
    int beg = row_off[node], end = row_off[node + 1];
    int eo = lane >> 5;        // edge parity in gather phase
    int cl = lane & 31;        // channel group: 4*cl .. 4*cl+3
    int h  = cl >> 3;          // my head in gather phase

    float mr0 = -1e30f, mr1 = -1e30f, mr2 = -1e30f, mr3 = -1e30f;
    float sr0 = 0.f, sr1 = 0.f, sr2 = 0.f, sr3 = 0.f;
    float acc0 = 0.f, acc1 = 0.f, acc2 = 0.f, acc3 = 0.f;

    for (int c = beg; c < end; c += CH1) {
        int cnt = min(CH1, end - c);
        int sA = 0, sB = 0;
        float scA0=-1e30f, scA1=-1e30f, scA2=-1e30f, scA3=-1e30f;
        float scB0=-1e30f, scB1=-1e30f, scB2=-1e30f, scB3=-1e30f;
        bool hasA = lane < cnt, hasB = lane + 64 < cnt;
        if (hasA) {
            sA = csr[c + lane];
            ssrc[lane] = sA;
            float4 av = *(const float4*)&as1[(size_t)sA * 4];
            float v;
            v = av.x + add0; scA0 = v > 0.f ? v : NEG * v;
            v = av.y + add1; scA1 = v > 0.f ? v : NEG * v;
            v = av.z + add2; scA2 = v > 0.f ? v : NEG * v;
            v = av.w + add3; scA3 = v > 0.f ? v : NEG * v;
        }
        if (hasB) {
            sB = csr[c + lane + 64];
            ssrc[lane + 64] = sB;
            float4 av = *(const float4*)&as1[(size_t)sB * 4];
            float v;
            v = av.x + add0; scB0 = v > 0.f ? v : NEG * v;
            v = av.y + add1; scB1 = v > 0.f ? v : NEG * v;
            v = av.z + add2; scB2 = v > 0.f ? v : NEG * v;
            v = av.w + add3; scB3 = v > 0.f ? v : NEG * v;
        }
        float lm0 = fmaxf(scA0, scB0), lm1 = fmaxf(scA1, scB1);
        float lm2 = fmaxf(scA2, scB2), lm3 = fmaxf(scA3, scB3);
        #pragma unroll
        for (int o = 32; o; o >>= 1) {
            lm0 = fmaxf(lm0, __shfl_xor(lm0, o));
            lm1 = fmaxf(lm1, __shfl_xor(lm1, o));
            lm2 = fmaxf(lm2, __shfl_xor(lm2, o));
            lm3 = fmaxf(lm3, __shfl_xor(lm3, o));
        }
        float nm0 = fmaxf(mr0, lm0), nm1 = fmaxf(mr1, lm1);
        float nm2 = fmaxf(mr2, lm2), nm3 = fmaxf(mr3, lm3);
        float om  = h == 0 ? mr0 : h == 1 ? mr1 : h == 2 ? mr2 : mr3;
        float nmh = h == 0 ? nm0 : h == 1 ? nm1 : h == 2 ? nm2 : nm3;
        float r = __expf(om - nmh);
        acc0 *= r; acc1 *= r; acc2 *= r; acc3 *= r;
        float ls0 = 0.f, ls1 = 0.f, ls2 = 0.f, ls3 = 0.f;
        if (hasA) {
            float p0 = __expf(scA0 - nm0), p1 = __expf(scA1 - nm1);
            float p2 = __expf(scA2 - nm2), p3 = __expf(scA3 - nm3);
            *(float4*)&sp[lane * 4] = make_float4(p0, p1, p2, p3);
            ls0 += p0; ls1 += p1; ls2 += p2; ls3 += p3;
        }
        if (hasB) {
            float p0 = __expf(scB0 - nm0), p1 = __expf(scB1 - nm1);
            float p2 = __expf(scB2 - nm2), p3 = __expf(scB3 - nm3);
            *(float4*)&sp[(lane + 64) * 4] = make_float4(p0, p1, p2, p3);
            ls0 += p0; ls1 += p1; ls2 += p2; ls3 += p3;
        }
        #pragma unroll
        for (int o = 32; o; o >>= 1) {
            ls0 += __shfl_xor(ls0, o);
            ls1 += __shfl_xor(ls1, o);
            ls2 += __shfl_xor(ls2, o);
            ls3 += __shfl_xor(ls3, o);
        }
        sr0 = sr0 * __expf(mr0 - nm0) + ls0;
        sr1 = sr1 * __expf(mr1 - nm1) + ls1;
        sr2 = sr2 * __expf(mr2 - nm2) + ls2;
        sr3 = sr3 * __expf(mr3 - nm3) + ls3;
        __threadfence_block();
        // ---- gather main: 8 edges per block, 4 loads in flight ----
        int nfull = cnt & ~7;
        for (int jj = 0; jj < nfull; jj += 8) {
            int j0 = jj + eo, j1 = jj + 2 + eo, j2 = jj + 4 + eo, j3 = jj + 6 + eo;
            int s0 = ssrc[j0], s1 = ssrc[j1], s2 = ssrc[j2], s3 = ssrc[j3];
            float p0 = sp[j0 * 4 + h], p1 = sp[j1 * 4 + h];
            float p2 = sp[j2 * 4 + h], p3 = sp[j3 * 4 + h];
            ushort4 u0 = *(const ushort4*)&h1h[(size_t)s0 * 128 + 4 * cl];
            ushort4 u1 = *(const ushort4*)&h1h[(size_t)s1 * 128 + 4 * cl];
            ushort4 u2 = *(const ushort4*)&h1h[(size_t)s2 * 128 + 4 * cl];
            ushort4 u3 = *(const ushort4*)&h1h[(size_t)s3 * 128 + 4 * cl];
            acc0 = fmaf(p0, h2f(u0.x), acc0);
            acc1 = fmaf(p0, h2f(u0.y), acc1);
            acc2 = fmaf(p0, h2f(u0.z), acc2);
            acc3 = fmaf(p0, h2f(u0.w), acc3);
            acc0 = fmaf(p1, h2f(u1.x), acc0);
            acc1 = fmaf(p1, h2f(u1.y), acc1);
            acc2 = fmaf(p1, h2f(u1.z), acc2);
            acc3 = fmaf(p1, h2f(u1.w), acc3);
            acc0 = fmaf(p2, h2f(u2.x), acc0);
            acc1 = fmaf(p2, h2f(u2.y), acc1);
            acc2 = fmaf(p2, h2f(u2.z), acc2);
            acc3 = fmaf(p2, h2f(u2.w), acc3);
            acc0 = fmaf(p3, h2f(u3.x), acc0);
            acc1 = fmaf(p3, h2f(u3.y), acc1);
            acc2 = fmaf(p3, h2f(u3.z), acc2);
            acc3 = fmaf(p3, h2f(u3.w), acc3);
        }
        // ---- gather tail ----
        for (int jj = nfull; jj < cnt; jj += 2) {
            int j = jj + eo;
            if (j < cnt) {
                int src = ssrc[j];
                float p = sp[j * 4 + h];
                ushort4 u = *(const ushort4*)&h1h[(size_t)src * 128 + 4 * cl];
                acc0 = fmaf(p, h2f(u.x), acc0);
                acc1 = fmaf(p, h2f(u.y), acc1);
                acc2 = fmaf(p, h2f(u.z), acc2);
                acc3 = fmaf(p, h2f(u.w), acc3);
            }
        }
        mr0 = nm0; mr1 = nm1; mr2 = nm2; mr3 = nm3;
    }
    // fold the two edge-parity halves
    acc0 += __shfl_xor(acc0, 32);
    acc1 += __shfl_xor(acc1, 32);
    acc2 += __shfl_xor(acc2, 32);
    acc3 += __shfl_xor(acc3, 32);
    float srh = h == 0 ? sr0 : h == 1 ? sr1 : h == 2 ? sr2 : sr3;
    float4 bb = *(const float4*)&b1[4 * cl];
    float v0 = acc0 / srh + bb.x;
    float v1 = acc1 / srh + bb.y;
    float v2 = acc2 / srh + bb.z;
    float v3 = acc3 / srh + bb.w;
    v0 = v0 > 0.f ? v0 : (__expf(v0) - 1.f);
    v1 = v1 > 0.f ? v1 : (__expf(v1) - 1.f);
    v2 = v2 > 0.f ? v2 : (__expf(v2) - 1.f);
    v3 = v3 > 0.f ? v3 : (__expf(v3) - 1.f);
    if (lane < 32)
        *(float4*)&z[(size_t)node * F1 + 4 * cl] = make_float4(v0, v1, v2, v3);
}

// ============ fused layer-2 GAT + log_softmax (fp16 gather) ============
// rec={src,p} uint2 at stride-2 (2-way aliasing = free). Gather main:
// 16 edges/block (4 per quarter-wave, 4 loads in flight), guarded tail.
__global__ __launch_bounds__(256) void k_gat2(
    const int* __restrict__ row_off, const int* __restrict__ csr,
    const float* __restrict__ as2, const float* __restrict__ ad2,
    const unsigned short* __restrict__ h2h, const float* __restrict__ b2,
    float* __restrict__ y, int n)
{
    int w = threadIdx.x >> 6, lane = threadIdx.x & 63;
    int node = blockIdx.x * 4 + w;
    if (node >= n) return;
    __shared__ unsigned s_rec_all[4][CH2 * 2];   // 4 KB
    unsigned* rec = s_rec_all[w];

    float addv = ad2[node];
    int beg = row_off[node], end = row_off[node + 1];
    int c2 = lane & 15, eo = lane >> 4;   // 4 edges in flight
    float mr = -1e30f, sr = 0.f, acc0 = 0.f, acc1 = 0.f;

    for (int c = beg; c < end; c += CH2) {
        int cnt = min(CH2, end - c);
        int sA = 0, sB = 0;
        float scA = -1e30f, scB = -1e30f;
        bool hasA = lane < cnt, hasB = lane + 64 < cnt;
        if (hasA) {
            sA = csr[c + lane];
            float v = as2[sA] + addv;
            scA = v > 0.f ? v : NEG * v;
        }
        if (hasB) {
            sB = csr[c + lane + 64];
            float v = as2[sB] + addv;
            scB = v > 0.f ? v : NEG * v;
        }
        float lm = fmaxf(scA, scB);
        #pragma unroll
        for (int o = 32; o; o >>= 1) lm = fmaxf(lm, __shfl_xor(lm, o));
        float nm = fmaxf(mr, lm);
        float r = __expf(mr - nm);
        acc0 *= r; acc1 *= r; sr *= r;
        float ls = 0.f;
        if (hasA) {
            float p = __expf(scA - nm);
            uint2 rr; rr.x = (unsigned)sA; rr.y = __float_as_uint(p);
            *(uint2*)&rec[lane * 2] = rr;
            ls += p;
        }
        if (hasB) {
            float p = __expf(scB - nm);
            uint2 rr; rr.x = (unsigned)sB; rr.y = __float_as_uint(p);
            *(uint2*)&rec[(lane + 64) * 2] = rr;
            ls += p;
        }
        #pragma unroll
        for (int o = 32; o; o >>= 1) ls += __shfl_xor(ls, o);
        sr += ls;
        __threadfence_block();
        // ---- gather main: 16 edges/block, 4 loads in flight ----
        int nfull = cnt & ~15;
        for (int jj = 0; jj < nfull; jj += 16) {
            uint2 r0 = *(uint2*)&rec[(jj + eo) * 2];
            uint2 r1 = *(uint2*)&rec[(jj + 4 + eo) * 2];
            uint2 r2 = *(uint2*)&rec[(jj + 8 + eo) * 2];
            uint2 r3 = *(uint2*)&rec[(jj + 12 + eo) * 2];
            ushort2 u0 = *(const ushort2*)&h2h[(size_t)r0.x * 32 + 2 * c2];
            ushort2 u1 = *(const ushort2*)&h2h[(size_t)r1.x * 32 + 2 * c2];
            ushort2 u2 = *(const ushort2*)&h2h[(size_t)r2.x * 32 + 2 * c2];
            ushort2 u3 = *(const ushort2*)&h2h[(size_t)r3.x * 32 + 2 * c2];
            float p0 = __uint_as_float(r0.y), p1 = __uint_as_float(r1.y);
            float p2 = __uint_as_float(r2.y), p3 = __uint_as_float(r3.y);
            acc0 = fmaf(p0, h2f(u0.x), acc0);
            acc1 = fmaf(p0, h2f(u0.y), acc1);
            acc0 = fmaf(p1, h2f(u1.x), acc0);
            acc1 = fmaf(p1, h2f(u1.y), acc1);
            acc0 = fmaf(p2, h2f(u2.x), acc0);
            acc1 = fmaf(p2, h2f(u2.y), acc1);
            acc0 = fmaf(p3, h2f(u3.x), acc0);
            acc1 = fmaf(p3, h2f(u3.y), acc1);
        }
        // ---- gather tail ----
        for (int jj = nfull; jj < cnt; jj += 4) {
            int j = jj + eo;
            if (j < cnt) {
                uint2 rr = *(uint2*)&rec[j * 2];
                float p = __uint_as_float(rr.y);
                ushort2 u = *(const ushort2*)&h2h[(size_t)rr.x * 32 + 2 * c2];
                acc0 = fmaf(p, h2f(u.x), acc0);
                acc1 = fmaf(p, h2f(u.y), acc1);
            }
        }
        mr = nm;
    }
    acc0 += __shfl_xor(acc0, 16); acc0 += __shfl_xor(acc0, 32);
    acc1 += __shfl_xor(acc1, 16); acc1 += __shfl_xor(acc1, 32);
    float v0 = acc0 / sr + b2[2 * c2];
    float v1 = acc1 / sr + b2[2 * c2 + 1];
    float m = fmaxf(v0, v1);
    #pragma unroll
    for (int o = 8; o; o >>= 1) m = fmaxf(m, __shfl_xor(m, o));
    float ss = __expf(v0 - m) + __expf(v1 - m);
    #pragma unroll
    for (int o = 8; o; o >>= 1) ss += __shfl_xor(ss, o);
    float lg = m + logf(ss);
    if (lane < 16)
        *(float2*)&y[(size_t)node * OUT_C + 2 * c2] = make_float2(v0 - lg, v1 - lg);
}

extern "C" void kernel_launch(void* const* d_in, const int* in_sizes, int n_in,
                              void* d_out, int out_size, void* d_ws, size_t ws_size,
                              hipStream_t stream) {
    const float* x    = (const float*)d_in[0];
    const int*   ei   = (const int*)d_in[1];
    const float* W1   = (const float*)d_in[2];
    const float* as1w = (const float*)d_in[3];
    const float* ad1w = (const float*)d_in[4];
    const float* b1   = (const float*)d_in[5];
    const float* W2   = (const float*)d_in[6];
    const float* as2w = (const float*)d_in[7];
    const float* ad2w = (const float*)d_in[8];
    const float* b2   = (const float*)d_in[9];
    float* out = (float*)d_out;

    int n  = in_sizes[0] / IN_C;
    int E_ = in_sizes[1] / 2;
    int EE = E_ + n;

    int NB = (n + (1 << SH) - 1) >> SH;        // buckets (<=512 for n<=131072)
    int NC = (EE + CHA - 1) / CHA;             // chunks
    int M  = NB * NC;
    int NBLK = (M + SCB - 1) / SCB;            // scan blocks (<=256)

    char* w = (char*)d_ws;
    size_t off = 0;
    auto take = [&](size_t elems) { void* p = w + off; off += ((elems * 4 + 255) & ~(size_t)255); return p; };
    int* bmat      = (int*)take((size_t)M);
    int* bsums     = (int*)take(256);
    unsigned* recs = (unsigned*)take((size_t)EE);
    int* row_off   = (int*)take((size_t)n + 1);
    int* csr       = (int*)take((size_t)EE);
    float* as1     = (float*)take((size_t)n * 4);
    float* ad1     = (float*)take((size_t)n * 4);
    unsigned short* h1h = (unsigned short*)take((size_t)n * 64);  // n*128 fp16
    float* z       = (float*)take((size_t)n * 128);
    unsigned short* h2h = (unsigned short*)take((size_t)n * 16);  // n*32 fp16
    float* as2     = (float*)take((size_t)n);
    float* ad2     = (float*)take((size_t)n);

    // CSR build: bucketed counting sort, no global atomics, parallel scan
    k_bhist   <<<NC, 256, 0, stream>>>(ei, bmat, E_, n, NB, NC);
    k_scanA   <<<NBLK, 256, 0, stream>>>(bmat, bsums, M);
    k_scanB   <<<1, 256, 0, stream>>>(bsums, NBLK);
    k_scanC   <<<(M + 255) / 256, 256, 0, stream>>>(bmat, bsums, M);
    k_bscatter<<<NC, 256, 0, stream>>>(ei, bmat, recs, E_, n, NB, NC);
    k_bfill   <<<NB, 256, 0, stream>>>(recs, bmat, row_off, csr, n, NB, NC, EE);

    // layer 1
    int nt = (n + 63) / 64;
    k_gemm1<<<nt * 2, 256, 0, stream>>>(x, W1, as1w, ad1w, h1h, as1, ad1, n);
    int gG = (n + 3) / 4;
    k_gat1<<<gG, 256, 0, stream>>>(row_off, csr, as1, ad1, h1h, b1, z, n);

    // layer 2
    k_gemm2<<<nt, 256, 0, stream>>>(z, W2, as2w, ad2w, h2h, as2, ad2, n);
    k_gat2<<<gG, 256, 0, stream>>>(row_off, csr, as2, ad2, h2h, b2, out, n);
}

// Round 12
// 369.541 us; speedup vs baseline: 1.1296x; 1.0851x over previous
//
#include <hip/hip_runtime.h>
#include <hip/hip_fp16.h>
#include <math.h>

#define IN_C   128
#define HEADS  4
#define F1     128   // HEADS*HID
#define OUT_C  32
#define NEG    0.2f
#define SH     8     // bucket = dst >> SH (256 dsts per bucket); needs n <= 2^17
#define CHA    8192  // edges per chunk in CSR pass A
#define SCB    4096  // elements per scan block (256 thr x 16)

// ---- fp16 helpers (RNE) ----
__device__ __forceinline__ unsigned short f2h(float f) {
    return __half_as_ushort(__float2half_rn(f));
}
__device__ __forceinline__ float h2f(unsigned short u) {
    return __half2float(__ushort_as_half(u));
}

// ============ CSR pass A1: per-chunk bucket histogram (LDS atomics only) ======
__global__ __launch_bounds__(256) void k_bhist(
    const int* __restrict__ ei, int* __restrict__ bmat, int E_, int n, int NB, int NC)
{
    __shared__ int h[512];
    int t = threadIdx.x, c = blockIdx.x;
    for (int i = t; i < NB; i += 256) h[i] = 0;
    __syncthreads();
    int e0 = c * CHA, e1 = min(e0 + CHA, E_ + n);
    for (int e = e0 + t; e < e1; e += 256) {
        int d = (e < E_) ? ei[E_ + e] : e - E_;
        atomicAdd(&h[d >> SH], 1);
    }
    __syncthreads();
    for (int i = t; i < NB; i += 256) bmat[i * NC + c] = h[i];
}

// ============ CSR pass A2: parallel exclusive scan of bmat (3 stages) ========
__global__ __launch_bounds__(256) void k_scanA(
    int* __restrict__ bmat, int* __restrict__ bsums, int M)
{
    __shared__ int sm[256];
    int t = threadIdx.x;
    int base = blockIdx.x * SCB + t * 16;
    int v[16];
    int s = 0;
    #pragma unroll
    for (int j = 0; j < 16; ++j) {
        int i = base + j;
        v[j] = (i < M) ? bmat[i] : 0;
        s += v[j];
    }
    sm[t] = s;
    __syncthreads();
    for (int off = 1; off < 256; off <<= 1) {
        int a = (t >= off) ? sm[t - off] : 0;
        __syncthreads();
        sm[t] += a;
        __syncthreads();
    }
    int excl = sm[t] - s;
    #pragma unroll
    for (int j = 0; j < 16; ++j) {
        int i = base + j;
        if (i < M) bmat[i] = excl;
        excl += v[j];
    }
    if (t == 255) bsums[blockIdx.x] = sm[255];
}

__global__ __launch_bounds__(256) void k_scanB(int* __restrict__ bsums, int NBLK)
{
    __shared__ int sm[256];
    int t = threadIdx.x;
    int v = (t < NBLK) ? bsums[t] : 0;
    sm[t] = v;
    __syncthreads();
    for (int off = 1; off < 256; off <<= 1) {
        int a = (t >= off) ? sm[t - off] : 0;
        __syncthreads();
        sm[t] += a;
        __syncthreads();
    }
    if (t < NBLK) bsums[t] = sm[t] - v;
}

__global__ __launch_bounds__(256) void k_scanC(
    int* __restrict__ bmat, const int* __restrict__ bsums, int M)
{
    int i = blockIdx.x * 256 + threadIdx.x;
    if (i < M) bmat[i] += bsums[i >> 12];   // 4096 = 1<<12
}

// ============ CSR pass A3: scatter packed recs into (bucket,chunk) ranges =====
__global__ __launch_bounds__(256) void k_bscatter(
    const int* __restrict__ ei, const int* __restrict__ bmat,
    unsigned* __restrict__ recs, int E_, int n, int NB, int NC)
{
    __shared__ int cur[512];
    int t = threadIdx.x, c = blockIdx.x;
    for (int i = t; i < NB; i += 256) cur[i] = bmat[i * NC + c];
    __syncthreads();
    int e0 = c * CHA, e1 = min(e0 + CHA, E_ + n);
    for (int e = e0 + t; e < e1; e += 256) {
        int s, d;
        if (e < E_) { s = ei[e]; d = ei[E_ + e]; } else { s = d = e - E_; }
        int b = d >> SH;
        int p = atomicAdd(&cur[b], 1);   // LDS atomic
        recs[p] = ((unsigned)(d & ((1 << SH) - 1)) << 17) | (unsigned)s;
    }
}

// ============ CSR pass B: per-bucket fine fill (one block owns one bucket) ====
__global__ __launch_bounds__(256) void k_bfill(
    const unsigned* __restrict__ recs, const int* __restrict__ bmat,
    int* __restrict__ row_off, int* __restrict__ csr, int n, int NB, int NC, int EE)
{
    __shared__ int deg[256];
    __shared__ int cur[256];
    int t = threadIdx.x, b = blockIdx.x;
    int r0 = bmat[b * NC];
    int r1 = (b + 1 < NB) ? bmat[(b + 1) * NC] : EE;
    deg[t] = 0;
    __syncthreads();
    for (int i = r0 + t; i < r1; i += 256)
        atomicAdd(&deg[recs[i] >> 17], 1);
    __syncthreads();
    int v = deg[t];
    for (int off = 1; off < 256; off <<= 1) {
        int a = (t >= off) ? deg[t - off] : 0;
        __syncthreads();
        deg[t] += a;
        __syncthreads();
    }
    int excl = deg[t] - v;
    int dst = (b << SH) + t;
    if (dst < n) row_off[dst] = r0 + excl;
    cur[t] = excl;
    if (b == NB - 1 && t == 0) row_off[n] = EE;
    __syncthreads();
    for (int i = r0 + t; i < r1; i += 256) {
        unsigned rec = recs[i];
        int dl = rec >> 17;
        int p = atomicAdd(&cur[dl], 1);   // LDS atomic
        csr[r0 + p] = (int)(rec & 0x1FFFFu);
    }
}

// ============ layer-1 GEMM: h1 = x@W1 (fp16 out) + fused att reduction =======
#define XS_STRIDE 68
__global__ __launch_bounds__(256) void k_gemm1(
    const float* __restrict__ x, const float* __restrict__ W,
    const float* __restrict__ as_w, const float* __restrict__ ad_w,
    unsigned short* __restrict__ h1h, float* __restrict__ as1,
    float* __restrict__ ad1, int n)
{
    __shared__ float Ws[128 * 64];
    __shared__ float xs[128 * XS_STRIDE];
    int t = threadIdx.x;
    int half = blockIdx.x & 1;
    int n0 = (blockIdx.x >> 1) * 64;

    for (int i = t; i < 128 * 16; i += 256) {
        int k = i >> 4, c4 = (i & 15) * 4;
        *(float4*)&Ws[k * 64 + c4] = *(const float4*)&W[k * 128 + half * 64 + c4];
    }
    for (int i = t; i < 64 * 32; i += 256) {
        int nl = i & 63, k4 = (i >> 6) * 4;
        int nn = n0 + nl;
        float4 v = (nn < n) ? *(const float4*)&x[(size_t)nn * 128 + k4]
                            : make_float4(0.f, 0.f, 0.f, 0.f);
        xs[(k4 + 0) * XS_STRIDE + nl] = v.x;
        xs[(k4 + 1) * XS_STRIDE + nl] = v.y;
        xs[(k4 + 2) * XS_STRIDE + nl] = v.z;
        xs[(k4 + 3) * XS_STRIDE + nl] = v.w;
    }
    __syncthreads();

    int tx = t & 15, ty = t >> 4;
    float acc[4][4] = {};
    #pragma unroll 8
    for (int k = 0; k < 128; ++k) {
        float4 a = *(float4*)&xs[k * XS_STRIDE + ty * 4];
        float4 b = *(float4*)&Ws[k * 64 + tx * 4];
        float av[4] = {a.x, a.y, a.z, a.w};
        float bv[4] = {b.x, b.y, b.z, b.w};
        #pragma unroll
        for (int i = 0; i < 4; ++i)
            #pragma unroll
            for (int j = 0; j < 4; ++j)
                acc[i][j] = fmaf(av[i], bv[j], acc[i][j]);
    }
    int cbase = half * 64 + tx * 4;
    float4 aws = *(const float4*)&as_w[cbase];
    float4 awd = *(const float4*)&ad_w[cbase];
    float sa[4], sd[4];
    #pragma unroll
    for (int i = 0; i < 4; ++i) {
        int nn = n0 + ty * 4 + i;
        sa[i] = acc[i][0]*aws.x + acc[i][1]*aws.y + acc[i][2]*aws.z + acc[i][3]*aws.w;
        sd[i] = acc[i][0]*awd.x + acc[i][1]*awd.y + acc[i][2]*awd.z + acc[i][3]*awd.w;
        if (nn < n) {
            ushort4 p;
            p.x = f2h(acc[i][0]); p.y = f2h(acc[i][1]);
            p.z = f2h(acc[i][2]); p.w = f2h(acc[i][3]);
            *(ushort4*)&h1h[(size_t)nn * 128 + cbase] = p;
        }
    }
    #pragma unroll
    for (int o = 1; o < 8; o <<= 1) {
        #pragma unroll
        for (int i = 0; i < 4; ++i) {
            sa[i] += __shfl_xor(sa[i], o);
            sd[i] += __shfl_xor(sd[i], o);
        }
    }
    if ((tx & 7) == 0) {
        int head = half * 2 + (tx >> 3);
        #pragma unroll
        for (int i = 0; i < 4; ++i) {
            int nn = n0 + ty * 4 + i;
            if (nn < n) {
                as1[(size_t)nn * 4 + head] = sa[i];
                ad1[(size_t)nn * 4 + head] = sd[i];
            }
        }
    }
}

// ============ layer-2 GEMM: h2 = z@W2 (fp16 out) + fused att reduction =======
#define ZS_STRIDE 66
__global__ __launch_bounds__(256) void k_gemm2(
    const float* __restrict__ z, const float* __restrict__ W,
    const float* __restrict__ as_w, const float* __restrict__ ad_w,
    unsigned short* __restrict__ h2h, float* __restrict__ as2,
    float* __restrict__ ad2, int n)
{
    __shared__ float Ws[128 * 32];
    __shared__ float zs[128 * ZS_STRIDE];
    int t = threadIdx.x;
    int n0 = blockIdx.x * 64;

    for (int i = t; i < 128 * 8; i += 256) {
        int k = i >> 3, c4 = (i & 7) * 4;
        *(float4*)&Ws[k * 32 + c4] = *(const float4*)&W[k * 32 + c4];
    }
    for (int i = t; i < 64 * 32; i += 256) {
        int nl = i & 63, k4 = (i >> 6) * 4;
        int nn = n0 + nl;
        float4 v = (nn < n) ? *(const float4*)&z[(size_t)nn * 128 + k4]
                            : make_float4(0.f, 0.f, 0.f, 0.f);
        zs[(k4 + 0) * ZS_STRIDE + nl] = v.x;
        zs[(k4 + 1) * ZS_STRIDE + nl] = v.y;
        zs[(k4 + 2) * ZS_STRIDE + nl] = v.z;
        zs[(k4 + 3) * ZS_STRIDE + nl] = v.w;
    }
    __syncthreads();

    int tx = t & 7, ty = t >> 3;
    float acc[2][4] = {};
    #pragma unroll 8
    for (int k = 0; k < 128; ++k) {
        float2 a = *(float2*)&zs[k * ZS_STRIDE + ty * 2];
        float4 b = *(float4*)&Ws[k * 32 + tx * 4];
        float av[2] = {a.x, a.y};
        float bv[4] = {b.x, b.y, b.z, b.w};
        #pragma unroll
        for (int i = 0; i < 2; ++i)
            #pragma unroll
            for (int j = 0; j < 4; ++j)
                acc[i][j] = fmaf(av[i], bv[j], acc[i][j]);
    }
    float4 aws = *(const float4*)&as_w[tx * 4];
    float4 awd = *(const float4*)&ad_w[tx * 4];
    float sa[2], sd[2];
    #pragma unroll
    for (int i = 0; i < 2; ++i) {
        int nn = n0 + ty * 2 + i;
        sa[i] = acc[i][0]*aws.x + acc[i][1]*aws.y + acc[i][2]*aws.z + acc[i][3]*aws.w;
        sd[i] = acc[i][0]*awd.x + acc[i][1]*awd.y + acc[i][2]*awd.z + acc[i][3]*awd.w;
        if (nn < n) {
            ushort4 p;
            p.x = f2h(acc[i][0]); p.y = f2h(acc[i][1]);
            p.z = f2h(acc[i][2]); p.w = f2h(acc[i][3]);
            *(ushort4*)&h2h[(size_t)nn * 32 + tx * 4] = p;
        }
    }
    #pragma unroll
    for (int o = 1; o < 8; o <<= 1) {
        #pragma unroll
        for (int i = 0; i < 2; ++i) {
            sa[i] += __shfl_xor(sa[i], o);
            sd[i] += __shfl_xor(sd[i], o);
        }
    }
    if (tx == 0) {
        #pragma unroll
        for (int i = 0; i < 2; ++i) {
            int nn = n0 + ty * 2 + i;
            if (nn < n) { as2[nn] = sa[i]; ad2[nn] = sd[i]; }
        }
    }
}

// ============ fused layer-1 GAT: softmax + fp16 gather + ELU ============
// 2 nodes per wave: 32 lanes per node, 8 nodes per block. Lane owns 4 ch
// (ushort4, 8 B; 32 lanes cover the 256 B row). Chunk = 32 edge slots
// (deg<=32 -> single pass). Gather: 4 edges unrolled per node -> 8 edges
// in flight per wave, no guards in main body, no epilogue folds.
__global__ __launch_bounds__(256) void k_gat1(
    const int* __restrict__ row_off, const int* __restrict__ csr,
    const float* __restrict__ as1, const float* __restrict__ ad1,
    const unsigned short* __restrict__ h1h, const float* __restrict__ b1,
    float* __restrict__ z, int n)
{
    int nb = threadIdx.x >> 5;      // node slot in block (0..7)
    int hl = threadIdx.x & 31;      // lane within node
    int node = blockIdx.x * 8 + nb;
    if (node >= n) return;
    __shared__ int   s_src[8][32];      // 1 KB
    __shared__ float s_p[8][32 * 4];    // 4 KB, sp[j*4+h] interleaved
    int* ssrc = s_src[nb];
    float* sp = s_p[nb];

    float4 addv = *(const float4*)&ad1[(size_t)node * 4];
    int beg = row_off[node], end = row_off[node + 1];
    int h = hl >> 3;                // my head in gather (4*hl channels)

    float mr0 = -1e30f, mr1 = -1e30f, mr2 = -1e30f, mr3 = -1e30f;
    float sr0 = 0.f, sr1 = 0.f, sr2 = 0.f, sr3 = 0.f;
    float acc0 = 0.f, acc1 = 0.f, acc2 = 0.f, acc3 = 0.f;

    for (int c = beg; c < end; c += 32) {
        int cnt = min(32, end - c);
        bool has = hl < cnt;
        int sA = 0;
        float sc0 = -1e30f, sc1 = -1e30f, sc2 = -1e30f, sc3 = -1e30f;
        if (has) {
            sA = csr[c + hl];
            ssrc[hl] = sA;
            float4 av = *(const float4*)&as1[(size_t)sA * 4];
            float v;
            v = av.x + addv.x; sc0 = v > 0.f ? v : NEG * v;
            v = av.y + addv.y; sc1 = v > 0.f ? v : NEG * v;
            v = av.z + addv.z; sc2 = v > 0.f ? v : NEG * v;
            v = av.w + addv.w; sc3 = v > 0.f ? v : NEG * v;
        }
        // 32-lane max reduce (xor<=16 stays within the half-wave)
        float lm0 = sc0, lm1 = sc1, lm2 = sc2, lm3 = sc3;
        #pragma unroll
        for (int o = 16; o; o >>= 1) {
            lm0 = fmaxf(lm0, __shfl_xor(lm0, o));
            lm1 = fmaxf(lm1, __shfl_xor(lm1, o));
            lm2 = fmaxf(lm2, __shfl_xor(lm2, o));
            lm3 = fmaxf(lm3, __shfl_xor(lm3, o));
        }
        float nm0 = fmaxf(mr0, lm0), nm1 = fmaxf(mr1, lm1);
        float nm2 = fmaxf(mr2, lm2), nm3 = fmaxf(mr3, lm3);
        float om  = h == 0 ? mr0 : h == 1 ? mr1 : h == 2 ? mr2 : mr3;
        float nmh = h == 0 ? nm0 : h == 1 ? nm1 : h == 2 ? nm2 : nm3;
        float r = __expf(om - nmh);
        acc0 *= r; acc1 *= r; acc2 *= r; acc3 *= r;
        float ls0 = 0.f, ls1 = 0.f, ls2 = 0.f, ls3 = 0.f;
        if (has) {
            float p0 = __expf(sc0 - nm0), p1 = __expf(sc1 - nm1);
            float p2 = __expf(sc2 - nm2), p3 = __expf(sc3 - nm3);
            *(float4*)&sp[hl * 4] = make_float4(p0, p1, p2, p3);
            ls0 = p0; ls1 = p1; ls2 = p2; ls3 = p3;
        }
        #pragma unroll
        for (int o = 16; o; o >>= 1) {
            ls0 += __shfl_xor(ls0, o);
            ls1 += __shfl_xor(ls1, o);
            ls2 += __shfl_xor(ls2, o);
            ls3 += __shfl_xor(ls3, o);
        }
        sr0 = sr0 * __expf(mr0 - nm0) + ls0;
        sr1 = sr1 * __expf(mr1 - nm1) + ls1;
        sr2 = sr2 * __expf(mr2 - nm2) + ls2;
        sr3 = sr3 * __expf(mr3 - nm3) + ls3;
        __threadfence_block();
        // ---- gather: 4 edges/group, all 32 lanes cooperate per edge ----
        int nfull = cnt & ~3;
        for (int jj = 0; jj < nfull; jj += 4) {
            int s0 = ssrc[jj], s1 = ssrc[jj + 1];
            int s2 = ssrc[jj + 2], s3 = ssrc[jj + 3];
            float p0 = sp[jj * 4 + h],       p1 = sp[(jj + 1) * 4 + h];
            float p2 = sp[(jj + 2) * 4 + h], p3 = sp[(jj + 3) * 4 + h];
            ushort4 u0 = *(const ushort4*)&h1h[(size_t)s0 * 128 + 4 * hl];
            ushort4 u1 = *(const ushort4*)&h1h[(size_t)s1 * 128 + 4 * hl];
            ushort4 u2 = *(const ushort4*)&h1h[(size_t)s2 * 128 + 4 * hl];
            ushort4 u3 = *(const ushort4*)&h1h[(size_t)s3 * 128 + 4 * hl];
            acc0 = fmaf(p0, h2f(u0.x), acc0);
            acc1 = fmaf(p0, h2f(u0.y), acc1);
            acc2 = fmaf(p0, h2f(u0.z), acc2);
            acc3 = fmaf(p0, h2f(u0.w), acc3);
            acc0 = fmaf(p1, h2f(u1.x), acc0);
            acc1 = fmaf(p1, h2f(u1.y), acc1);
            acc2 = fmaf(p1, h2f(u1.z), acc2);
            acc3 = fmaf(p1, h2f(u1.w), acc3);
            acc0 = fmaf(p2, h2f(u2.x), acc0);
            acc1 = fmaf(p2, h2f(u2.y), acc1);
            acc2 = fmaf(p2, h2f(u2.z), acc2);
            acc3 = fmaf(p2, h2f(u2.w), acc3);
            acc0 = fmaf(p3, h2f(u3.x), acc0);
            acc1 = fmaf(p3, h2f(u3.y), acc1);
            acc2 = fmaf(p3, h2f(u3.z), acc2);
            acc3 = fmaf(p3, h2f(u3.w), acc3);
        }
        for (int j = nfull; j < cnt; ++j) {
            int src = ssrc[j];
            float p = sp[j * 4 + h];
            ushort4 u = *(const ushort4*)&h1h[(size_t)src * 128 + 4 * hl];
            acc0 = fmaf(p, h2f(u.x), acc0);
            acc1 = fmaf(p, h2f(u.y), acc1);
            acc2 = fmaf(p, h2f(u.z), acc2);
            acc3 = fmaf(p, h2f(u.w), acc3);
        }
        mr0 = nm0; mr1 = nm1; mr2 = nm2; mr3 = nm3;
    }
    float srh = h == 0 ? sr0 : h == 1 ? sr1 : h == 2 ? sr2 : sr3;
    float4 bb = *(const float4*)&b1[4 * hl];
    float v0 = acc0 / srh + bb.x;
    float v1 = acc1 / srh + bb.y;
    float v2 = acc2 / srh + bb.z;
    float v3 = acc3 / srh + bb.w;
    v0 = v0 > 0.f ? v0 : (__expf(v0) - 1.f);
    v1 = v1 > 0.f ? v1 : (__expf(v1) - 1.f);
    v2 = v2 > 0.f ? v2 : (__expf(v2) - 1.f);
    v3 = v3 > 0.f ? v3 : (__expf(v3) - 1.f);
    *(float4*)&z[(size_t)node * F1 + 4 * hl] = make_float4(v0, v1, v2, v3);
}

// ============ fused layer-2 GAT + log_softmax (fp16 gather) ============
// 2 nodes per wave: 32 lanes per node, 1 ch per lane; chunk = 32 slots;
// gather 4 edges unrolled per node.
__global__ __launch_bounds__(256) void k_gat2(
    const int* __restrict__ row_off, const int* __restrict__ csr,
    const float* __restrict__ as2, const float* __restrict__ ad2,
    const unsigned short* __restrict__ h2h, const float* __restrict__ b2,
    float* __restrict__ y, int n)
{
    int nb = threadIdx.x >> 5;
    int hl = threadIdx.x & 31;
    int node = blockIdx.x * 8 + nb;
    if (node >= n) return;
    __shared__ int   s_src[8][32];   // 1 KB
    __shared__ float s_p[8][32];     // 1 KB
    int* ssrc = s_src[nb];
    float* sp = s_p[nb];

    float addv = ad2[node];
    int beg = row_off[node], end = row_off[node + 1];
    float mr = -1e30f, sr = 0.f, acc = 0.f;

    for (int c = beg; c < end; c += 32) {
        int cnt = min(32, end - c);
        bool has = hl < cnt;
        float sc = -1e30f;
        if (has) {
            int sA = csr[c + hl];
            ssrc[hl] = sA;
            float v = as2[sA] + addv;
            sc = v > 0.f ? v : NEG * v;
        }
        float lm = sc;
        #pragma unroll
        for (int o = 16; o; o >>= 1) lm = fmaxf(lm, __shfl_xor(lm, o));
        float nm = fmaxf(mr, lm);
        float r = __expf(mr - nm);
        acc *= r; sr *= r;
        float ls = 0.f;
        if (has) {
            float p = __expf(sc - nm);
            sp[hl] = p;
            ls = p;
        }
        #pragma unroll
        for (int o = 16; o; o >>= 1) ls += __shfl_xor(ls, o);
        sr += ls;
        __threadfence_block();
        int nfull = cnt & ~3;
        for (int jj = 0; jj < nfull; jj += 4) {
            int s0 = ssrc[jj], s1 = ssrc[jj + 1];
            int s2 = ssrc[jj + 2], s3 = ssrc[jj + 3];
            float p0 = sp[jj], p1 = sp[jj + 1];
            float p2 = sp[jj + 2], p3 = sp[jj + 3];
            unsigned short u0 = h2h[(size_t)s0 * 32 + hl];
            unsigned short u1 = h2h[(size_t)s1 * 32 + hl];
            unsigned short u2 = h2h[(size_t)s2 * 32 + hl];
            unsigned short u3 = h2h[(size_t)s3 * 32 + hl];
            acc = fmaf(p0, h2f(u0), acc);
            acc = fmaf(p1, h2f(u1), acc);
            acc = fmaf(p2, h2f(u2), acc);
            acc = fmaf(p3, h2f(u3), acc);
        }
        for (int j = nfull; j < cnt; ++j) {
            acc = fmaf(sp[j], h2f(h2h[(size_t)ssrc[j] * 32 + hl]), acc);
        }
        mr = nm;
    }
    float v = acc / sr + b2[hl];
    // log_softmax over the 32 channels held by this half-wave
    float m = v;
    #pragma unroll
    for (int o = 16; o; o >>= 1) m = fmaxf(m, __shfl_xor(m, o));
    float ex = __expf(v - m), ss = ex;
    #pragma unroll
    for (int o = 16; o; o >>= 1) ss += __shfl_xor(ss, o);
    y[(size_t)node * OUT_C + hl] = v - m - logf(ss);
}

extern "C" void kernel_launch(void* const* d_in, const int* in_sizes, int n_in,
                              void* d_out, int out_size, void* d_ws, size_t ws_size,
                              hipStream_t stream) {
    const float* x    = (const float*)d_in[0];
    const int*   ei   = (const int*)d_in[1];
    const float* W1   = (const float*)d_in[2];
    const float* as1w = (const float*)d_in[3];
    const float* ad1w = (const float*)d_in[4];
    const float* b1   = (const float*)d_in[5];
    const float* W2   = (const float*)d_in[6];
    const float* as2w = (const float*)d_in[7];
    const float* ad2w = (const float*)d_in[8];
    const float* b2   = (const float*)d_in[9];
    float* out = (float*)d_out;

    int n  = in_sizes[0] / IN_C;
    int E_ = in_sizes[1] / 2;
    int EE = E_ + n;

    int NB = (n + (1 << SH) - 1) >> SH;        // buckets (<=512 for n<=131072)
    int NC = (EE + CHA - 1) / CHA;             // chunks
    int M  = NB * NC;
    int NBLK = (M + SCB - 1) / SCB;            // scan blocks (<=256)

    char* w = (char*)d_ws;
    size_t off = 0;
    auto take = [&](size_t elems) { void* p = w + off; off += ((elems * 4 + 255) & ~(size_t)255); return p; };
    int* bmat      = (int*)take((size_t)M);
    int* bsums     = (int*)take(256);
    unsigned* recs = (unsigned*)take((size_t)EE);
    int* row_off   = (int*)take((size_t)n + 1);
    int* csr       = (int*)take((size_t)EE);
    float* as1     = (float*)take((size_t)n * 4);
    float* ad1     = (float*)take((size_t)n * 4);
    unsigned short* h1h = (unsigned short*)take((size_t)n * 64);  // n*128 fp16
    float* z       = (float*)take((size_t)n * 128);
    unsigned short* h2h = (unsigned short*)take((size_t)n * 16);  // n*32 fp16
    float* as2     = (float*)take((size_t)n);
    float* ad2     = (float*)take((size_t)n);

    // CSR build: bucketed counting sort, no global atomics, parallel scan
    k_bhist   <<<NC, 256, 0, stream>>>(ei, bmat, E_, n, NB, NC);
    k_scanA   <<<NBLK, 256, 0, stream>>>(bmat, bsums, M);
    k_scanB   <<<1, 256, 0, stream>>>(bsums, NBLK);
    k_scanC   <<<(M + 255) / 256, 256, 0, stream>>>(bmat, bsums, M);
    k_bscatter<<<NC, 256, 0, stream>>>(ei, bmat, recs, E_, n, NB, NC);
    k_bfill   <<<NB, 256, 0, stream>>>(recs, bmat, row_off, csr, n, NB, NC, EE);

    // layer 1
    int nt = (n + 63) / 64;
    k_gemm1<<<nt * 2, 256, 0, stream>>>(x, W1, as1w, ad1w, h1h, as1, ad1, n);
    int gG = (n + 7) / 8;
    k_gat1<<<gG, 256, 0, stream>>>(row_off, csr, as1, ad1, h1h, b1, z, n);

    // layer 2
    k_gemm2<<<nt, 256, 0, stream>>>(z, W2, as2w, ad2w, h2h, as2, ad2, n);
    k_gat2<<<gG, 256, 0, stream>>>(row_off, csr, as2, ad2, h2h, b2, out, n);
}

// Round 13
// 352.136 us; speedup vs baseline: 1.1854x; 1.0494x over previous
//
#include <hip/hip_runtime.h>
#include <hip/hip_fp16.h>
#include <math.h>

#define IN_C   128
#define HEADS  4
#define F1     128   // HEADS*HID
#define OUT_C  32
#define NEG    0.2f
#define SH     8     // bucket = dst >> SH (256 dsts per bucket); needs n <= 2^17
#define CHA    8192  // edges per chunk in CSR pass A
#define SCB    4096  // elements per scan block (256 thr x 16)

// ---- fp16 helpers (RNE) ----
__device__ __forceinline__ unsigned short f2h(float f) {
    return __half_as_ushort(__float2half_rn(f));
}
__device__ __forceinline__ float h2f(unsigned short u) {
    return __half2float(__ushort_as_half(u));
}
__device__ __forceinline__ unsigned pk2(float a, float b) {
    return (unsigned)f2h(a) | ((unsigned)f2h(b) << 16);
}
typedef _Float16 h2v __attribute__((ext_vector_type(2)));
__device__ __forceinline__ h2v u2h2(unsigned u) {
    h2v r; __builtin_memcpy(&r, &u, 4); return r;
}
__device__ __forceinline__ float dot2(unsigned a, unsigned b, float c) {
    return __builtin_amdgcn_fdot2(u2h2(a), u2h2(b), c, false);
}

// ============ CSR pass A1: per-chunk bucket histogram (LDS atomics only) ======
__global__ __launch_bounds__(256) void k_bhist(
    const int* __restrict__ ei, int* __restrict__ bmat, int E_, int n, int NB, int NC)
{
    __shared__ int h[512];
    int t = threadIdx.x, c = blockIdx.x;
    for (int i = t; i < NB; i += 256) h[i] = 0;
    __syncthreads();
    int e0 = c * CHA, e1 = min(e0 + CHA, E_ + n);
    for (int e = e0 + t; e < e1; e += 256) {
        int d = (e < E_) ? ei[E_ + e] : e - E_;
        atomicAdd(&h[d >> SH], 1);
    }
    __syncthreads();
    for (int i = t; i < NB; i += 256) bmat[i * NC + c] = h[i];
}

// ============ CSR pass A2: parallel exclusive scan of bmat (3 stages) ========
__global__ __launch_bounds__(256) void k_scanA(
    int* __restrict__ bmat, int* __restrict__ bsums, int M)
{
    __shared__ int sm[256];
    int t = threadIdx.x;
    int base = blockIdx.x * SCB + t * 16;
    int v[16];
    int s = 0;
    #pragma unroll
    for (int j = 0; j < 16; ++j) {
        int i = base + j;
        v[j] = (i < M) ? bmat[i] : 0;
        s += v[j];
    }
    sm[t] = s;
    __syncthreads();
    for (int off = 1; off < 256; off <<= 1) {
        int a = (t >= off) ? sm[t - off] : 0;
        __syncthreads();
        sm[t] += a;
        __syncthreads();
    }
    int excl = sm[t] - s;
    #pragma unroll
    for (int j = 0; j < 16; ++j) {
        int i = base + j;
        if (i < M) bmat[i] = excl;
        excl += v[j];
    }
    if (t == 255) bsums[blockIdx.x] = sm[255];
}

__global__ __launch_bounds__(256) void k_scanB(int* __restrict__ bsums, int NBLK)
{
    __shared__ int sm[256];
    int t = threadIdx.x;
    int v = (t < NBLK) ? bsums[t] : 0;
    sm[t] = v;
    __syncthreads();
    for (int off = 1; off < 256; off <<= 1) {
        int a = (t >= off) ? sm[t - off] : 0;
        __syncthreads();
        sm[t] += a;
        __syncthreads();
    }
    if (t < NBLK) bsums[t] = sm[t] - v;
}

__global__ __launch_bounds__(256) void k_scanC(
    int* __restrict__ bmat, const int* __restrict__ bsums, int M)
{
    int i = blockIdx.x * 256 + threadIdx.x;
    if (i < M) bmat[i] += bsums[i >> 12];   // 4096 = 1<<12
}

// ============ CSR pass A3: scatter packed recs into (bucket,chunk) ranges =====
__global__ __launch_bounds__(256) void k_bscatter(
    const int* __restrict__ ei, const int* __restrict__ bmat,
    unsigned* __restrict__ recs, int E_, int n, int NB, int NC)
{
    __shared__ int cur[512];
    int t = threadIdx.x, c = blockIdx.x;
    for (int i = t; i < NB; i += 256) cur[i] = bmat[i * NC + c];
    __syncthreads();
    int e0 = c * CHA, e1 = min(e0 + CHA, E_ + n);
    for (int e = e0 + t; e < e1; e += 256) {
        int s, d;
        if (e < E_) { s = ei[e]; d = ei[E_ + e]; } else { s = d = e - E_; }
        int b = d >> SH;
        int p = atomicAdd(&cur[b], 1);   // LDS atomic
        recs[p] = ((unsigned)(d & ((1 << SH) - 1)) << 17) | (unsigned)s;
    }
}

// ============ CSR pass B: per-bucket fine fill (one block owns one bucket) ====
__global__ __launch_bounds__(256) void k_bfill(
    const unsigned* __restrict__ recs, const int* __restrict__ bmat,
    int* __restrict__ row_off, int* __restrict__ csr, int n, int NB, int NC, int EE)
{
    __shared__ int deg[256];
    __shared__ int cur[256];
    int t = threadIdx.x, b = blockIdx.x;
    int r0 = bmat[b * NC];
    int r1 = (b + 1 < NB) ? bmat[(b + 1) * NC] : EE;
    deg[t] = 0;
    __syncthreads();
    for (int i = r0 + t; i < r1; i += 256)
        atomicAdd(&deg[recs[i] >> 17], 1);
    __syncthreads();
    int v = deg[t];
    for (int off = 1; off < 256; off <<= 1) {
        int a = (t >= off) ? deg[t - off] : 0;
        __syncthreads();
        deg[t] += a;
        __syncthreads();
    }
    int excl = deg[t] - v;
    int dst = (b << SH) + t;
    if (dst < n) row_off[dst] = r0 + excl;
    cur[t] = excl;
    if (b == NB - 1 && t == 0) row_off[n] = EE;
    __syncthreads();
    for (int i = r0 + t; i < r1; i += 256) {
        unsigned rec = recs[i];
        int dl = rec >> 17;
        int p = atomicAdd(&cur[dl], 1);   // LDS atomic
        csr[r0 + p] = (int)(rec & 0x1FFFFu);
    }
}

// ============ layer-1 GEMM: h1 = x@W1 via v_dot2_f32_f16 + fused att ========
// fp16-pair LDS staging: xs2[k2][node] / Ws2[k2][col] pack (2k,2k+1).
// 16 dot2 per k2 (2 MACs each), fp32 accumulate. 32KB LDS -> 4 blocks/CU.
__global__ __launch_bounds__(256) void k_gemm1(
    const float* __restrict__ x, const float* __restrict__ W,
    const float* __restrict__ as_w, const float* __restrict__ ad_w,
    unsigned short* __restrict__ h1h, float* __restrict__ as1,
    float* __restrict__ ad1, int n)
{
    __shared__ unsigned Ws2[64 * 64];   // 16 KB [k2][col]
    __shared__ unsigned xs2[64 * 64];   // 16 KB [k2][node]
    int t = threadIdx.x;
    int half = blockIdx.x & 1;
    int n0 = (blockIdx.x >> 1) * 64;

    // stage W half, packed pairs along k
    for (int i = t; i < 64 * 16; i += 256) {
        int k2 = i >> 4, c4 = (i & 15) * 4;
        const float* w0 = &W[(2 * k2) * 128 + half * 64 + c4];
        const float* w1 = &W[(2 * k2 + 1) * 128 + half * 64 + c4];
        float4 a = *(const float4*)w0;
        float4 b = *(const float4*)w1;
        uint4 p;
        p.x = pk2(a.x, b.x); p.y = pk2(a.y, b.y);
        p.z = pk2(a.z, b.z); p.w = pk2(a.w, b.w);
        *(uint4*)&Ws2[k2 * 64 + c4] = p;
    }
    // stage x tile transposed, packed pairs along k
    for (int i = t; i < 64 * 32; i += 256) {
        int nl = i & 63, k4 = (i >> 6) * 4;
        int nn = n0 + nl;
        float4 v = (nn < n) ? *(const float4*)&x[(size_t)nn * 128 + k4]
                            : make_float4(0.f, 0.f, 0.f, 0.f);
        xs2[(k4 >> 1) * 64 + nl]       = pk2(v.x, v.y);
        xs2[((k4 >> 1) + 1) * 64 + nl] = pk2(v.z, v.w);
    }
    __syncthreads();

    int tx = t & 15, ty = t >> 4;
    float acc[4][4] = {};
    #pragma unroll 4
    for (int k2 = 0; k2 < 64; ++k2) {
        uint4 a = *(uint4*)&xs2[k2 * 64 + ty * 4];
        uint4 b = *(uint4*)&Ws2[k2 * 64 + tx * 4];
        unsigned av[4] = {a.x, a.y, a.z, a.w};
        unsigned bv[4] = {b.x, b.y, b.z, b.w};
        #pragma unroll
        for (int i = 0; i < 4; ++i)
            #pragma unroll
            for (int j = 0; j < 4; ++j)
                acc[i][j] = dot2(av[i], bv[j], acc[i][j]);
    }
    int cbase = half * 64 + tx * 4;
    float4 aws = *(const float4*)&as_w[cbase];
    float4 awd = *(const float4*)&ad_w[cbase];
    float sa[4], sd[4];
    #pragma unroll
    for (int i = 0; i < 4; ++i) {
        int nn = n0 + ty * 4 + i;
        sa[i] = acc[i][0]*aws.x + acc[i][1]*aws.y + acc[i][2]*aws.z + acc[i][3]*aws.w;
        sd[i] = acc[i][0]*awd.x + acc[i][1]*awd.y + acc[i][2]*awd.z + acc[i][3]*awd.w;
        if (nn < n) {
            ushort4 p;
            p.x = f2h(acc[i][0]); p.y = f2h(acc[i][1]);
            p.z = f2h(acc[i][2]); p.w = f2h(acc[i][3]);
            *(ushort4*)&h1h[(size_t)nn * 128 + cbase] = p;
        }
    }
    #pragma unroll
    for (int o = 1; o < 8; o <<= 1) {
        #pragma unroll
        for (int i = 0; i < 4; ++i) {
            sa[i] += __shfl_xor(sa[i], o);
            sd[i] += __shfl_xor(sd[i], o);
        }
    }
    if ((tx & 7) == 0) {
        int head = half * 2 + (tx >> 3);
        #pragma unroll
        for (int i = 0; i < 4; ++i) {
            int nn = n0 + ty * 4 + i;
            if (nn < n) {
                as1[(size_t)nn * 4 + head] = sa[i];
                ad1[(size_t)nn * 4 + head] = sd[i];
            }
        }
    }
}

// ============ layer-2 GEMM: h2 = z@W2 via v_dot2_f32_f16 + fused att ========
__global__ __launch_bounds__(256) void k_gemm2(
    const float* __restrict__ z, const float* __restrict__ W,
    const float* __restrict__ as_w, const float* __restrict__ ad_w,
    unsigned short* __restrict__ h2h, float* __restrict__ as2,
    float* __restrict__ ad2, int n)
{
    __shared__ unsigned Ws2[64 * 32];   // 8 KB [k2][col]
    __shared__ unsigned zs2[64 * 64];   // 16 KB [k2][node]
    int t = threadIdx.x;
    int n0 = blockIdx.x * 64;

    for (int i = t; i < 64 * 8; i += 256) {
        int k2 = i >> 3, c4 = (i & 7) * 4;
        float4 a = *(const float4*)&W[(2 * k2) * 32 + c4];
        float4 b = *(const float4*)&W[(2 * k2 + 1) * 32 + c4];
        uint4 p;
        p.x = pk2(a.x, b.x); p.y = pk2(a.y, b.y);
        p.z = pk2(a.z, b.z); p.w = pk2(a.w, b.w);
        *(uint4*)&Ws2[k2 * 32 + c4] = p;
    }
    for (int i = t; i < 64 * 32; i += 256) {
        int nl = i & 63, k4 = (i >> 6) * 4;
        int nn = n0 + nl;
        float4 v = (nn < n) ? *(const float4*)&z[(size_t)nn * 128 + k4]
                            : make_float4(0.f, 0.f, 0.f, 0.f);
        zs2[(k4 >> 1) * 64 + nl]       = pk2(v.x, v.y);
        zs2[((k4 >> 1) + 1) * 64 + nl] = pk2(v.z, v.w);
    }
    __syncthreads();

    int tx = t & 7, ty = t >> 3;
    float acc[2][4] = {};
    #pragma unroll 4
    for (int k2 = 0; k2 < 64; ++k2) {
        uint2 a = *(uint2*)&zs2[k2 * 64 + ty * 2];
        uint4 b = *(uint4*)&Ws2[k2 * 32 + tx * 4];
        unsigned av[2] = {a.x, a.y};
        unsigned bv[4] = {b.x, b.y, b.z, b.w};
        #pragma unroll
        for (int i = 0; i < 2; ++i)
            #pragma unroll
            for (int j = 0; j < 4; ++j)
                acc[i][j] = dot2(av[i], bv[j], acc[i][j]);
    }
    float4 aws = *(const float4*)&as_w[tx * 4];
    float4 awd = *(const float4*)&ad_w[tx * 4];
    float sa[2], sd[2];
    #pragma unroll
    for (int i = 0; i < 2; ++i) {
        int nn = n0 + ty * 2 + i;
        sa[i] = acc[i][0]*aws.x + acc[i][1]*aws.y + acc[i][2]*aws.z + acc[i][3]*aws.w;
        sd[i] = acc[i][0]*awd.x + acc[i][1]*awd.y + acc[i][2]*awd.z + acc[i][3]*awd.w;
        if (nn < n) {
            ushort4 p;
            p.x = f2h(acc[i][0]); p.y = f2h(acc[i][1]);
            p.z = f2h(acc[i][2]); p.w = f2h(acc[i][3]);
            *(ushort4*)&h2h[(size_t)nn * 32 + tx * 4] = p;
        }
    }
    #pragma unroll
    for (int o = 1; o < 8; o <<= 1) {
        #pragma unroll
        for (int i = 0; i < 2; ++i) {
            sa[i] += __shfl_xor(sa[i], o);
            sd[i] += __shfl_xor(sd[i], o);
        }
    }
    if (tx == 0) {
        #pragma unroll
        for (int i = 0; i < 2; ++i) {
            int nn = n0 + ty * 2 + i;
            if (nn < n) { as2[nn] = sa[i]; ad2[nn] = sd[i]; }
        }
    }
}

// ============ fused layer-1 GAT: softmax + fp16 gather + ELU ============
// 2 nodes per wave: 32 lanes per node, 8 nodes per block.
__global__ __launch_bounds__(256) void k_gat1(
    const int* __restrict__ row_off, const int* __restrict__ csr,
    const float* __restrict__ as1, const float* __restrict__ ad1,
    const unsigned short* __restrict__ h1h, const float* __restrict__ b1,
    float* __restrict__ z, int n)
{
    int nb = threadIdx.x >> 5;      // node slot in block (0..7)
    int hl = threadIdx.x & 31;      // lane within node
    int node = blockIdx.x * 8 + nb;
    if (node >= n) return;
    __shared__ int   s_src[8][32];      // 1 KB
    __shared__ float s_p[8][32 * 4];    // 4 KB, sp[j*4+h] interleaved
    int* ssrc = s_src[nb];
    float* sp = s_p[nb];

    float4 addv = *(const float4*)&ad1[(size_t)node * 4];
    int beg = row_off[node], end = row_off[node + 1];
    int h = hl >> 3;                // my head in gather (4*hl channels)

    float mr0 = -1e30f, mr1 = -1e30f, mr2 = -1e30f, mr3 = -1e30f;
    float sr0 = 0.f, sr1 = 0.f, sr2 = 0.f, sr3 = 0.f;
    float acc0 = 0.f, acc1 = 0.f, acc2 = 0.f, acc3 = 0.f;

    for (int c = beg; c < end; c += 32) {
        int cnt = min(32, end - c);
        bool has = hl < cnt;
        int sA = 0;
        float sc0 = -1e30f, sc1 = -1e30f, sc2 = -1e30f, sc3 = -1e30f;
        if (has) {
            sA = csr[c + hl];
            ssrc[hl] = sA;
            float4 av = *(const float4*)&as1[(size_t)sA * 4];
            float v;
            v = av.x + addv.x; sc0 = v > 0.f ? v : NEG * v;
            v = av.y + addv.y; sc1 = v > 0.f ? v : NEG * v;
            v = av.z + addv.z; sc2 = v > 0.f ? v : NEG * v;
            v = av.w + addv.w; sc3 = v > 0.f ? v : NEG * v;
        }
        float lm0 = sc0, lm1 = sc1, lm2 = sc2, lm3 = sc3;
        #pragma unroll
        for (int o = 16; o; o >>= 1) {
            lm0 = fmaxf(lm0, __shfl_xor(lm0, o));
            lm1 = fmaxf(lm1, __shfl_xor(lm1, o));
            lm2 = fmaxf(lm2, __shfl_xor(lm2, o));
            lm3 = fmaxf(lm3, __shfl_xor(lm3, o));
        }
        float nm0 = fmaxf(mr0, lm0), nm1 = fmaxf(mr1, lm1);
        float nm2 = fmaxf(mr2, lm2), nm3 = fmaxf(mr3, lm3);
        float om  = h == 0 ? mr0 : h == 1 ? mr1 : h == 2 ? mr2 : mr3;
        float nmh = h == 0 ? nm0 : h == 1 ? nm1 : h == 2 ? nm2 : nm3;
        float r = __expf(om - nmh);
        acc0 *= r; acc1 *= r; acc2 *= r; acc3 *= r;
        float ls0 = 0.f, ls1 = 0.f, ls2 = 0.f, ls3 = 0.f;
        if (has) {
            float p0 = __expf(sc0 - nm0), p1 = __expf(sc1 - nm1);
            float p2 = __expf(sc2 - nm2), p3 = __expf(sc3 - nm3);
            *(float4*)&sp[hl * 4] = make_float4(p0, p1, p2, p3);
            ls0 = p0; ls1 = p1; ls2 = p2; ls3 = p3;
        }
        #pragma unroll
        for (int o = 16; o; o >>= 1) {
            ls0 += __shfl_xor(ls0, o);
            ls1 += __shfl_xor(ls1, o);
            ls2 += __shfl_xor(ls2, o);
            ls3 += __shfl_xor(ls3, o);
        }
        sr0 = sr0 * __expf(mr0 - nm0) + ls0;
        sr1 = sr1 * __expf(mr1 - nm1) + ls1;
        sr2 = sr2 * __expf(mr2 - nm2) + ls2;
        sr3 = sr3 * __expf(mr3 - nm3) + ls3;
        __threadfence_block();
        int nfull = cnt & ~3;
        for (int jj = 0; jj < nfull; jj += 4) {
            int s0 = ssrc[jj], s1 = ssrc[jj + 1];
            int s2 = ssrc[jj + 2], s3 = ssrc[jj + 3];
            float p0 = sp[jj * 4 + h],       p1 = sp[(jj + 1) * 4 + h];
            float p2 = sp[(jj + 2) * 4 + h], p3 = sp[(jj + 3) * 4 + h];
            ushort4 u0 = *(const ushort4*)&h1h[(size_t)s0 * 128 + 4 * hl];
            ushort4 u1 = *(const ushort4*)&h1h[(size_t)s1 * 128 + 4 * hl];
            ushort4 u2 = *(const ushort4*)&h1h[(size_t)s2 * 128 + 4 * hl];
            ushort4 u3 = *(const ushort4*)&h1h[(size_t)s3 * 128 + 4 * hl];
            acc0 = fmaf(p0, h2f(u0.x), acc0);
            acc1 = fmaf(p0, h2f(u0.y), acc1);
            acc2 = fmaf(p0, h2f(u0.z), acc2);
            acc3 = fmaf(p0, h2f(u0.w), acc3);
            acc0 = fmaf(p1, h2f(u1.x), acc0);
            acc1 = fmaf(p1, h2f(u1.y), acc1);
            acc2 = fmaf(p1, h2f(u1.z), acc2);
            acc3 = fmaf(p1, h2f(u1.w), acc3);
            acc0 = fmaf(p2, h2f(u2.x), acc0);
            acc1 = fmaf(p2, h2f(u2.y), acc1);
            acc2 = fmaf(p2, h2f(u2.z), acc2);
            acc3 = fmaf(p2, h2f(u2.w), acc3);
            acc0 = fmaf(p3, h2f(u3.x), acc0);
            acc1 = fmaf(p3, h2f(u3.y), acc1);
            acc2 = fmaf(p3, h2f(u3.z), acc2);
            acc3 = fmaf(p3, h2f(u3.w), acc3);
        }
        for (int j = nfull; j < cnt; ++j) {
            int src = ssrc[j];
            float p = sp[j * 4 + h];
            ushort4 u = *(const ushort4*)&h1h[(size_t)src * 128 + 4 * hl];
            acc0 = fmaf(p, h2f(u.x), acc0);
            acc1 = fmaf(p, h2f(u.y), acc1);
            acc2 = fmaf(p, h2f(u.z), acc2);
            acc3 = fmaf(p, h2f(u.w), acc3);
        }
        mr0 = nm0; mr1 = nm1; mr2 = nm2; mr3 = nm3;
    }
    float srh = h == 0 ? sr0 : h == 1 ? sr1 : h == 2 ? sr2 : sr3;
    float4 bb = *(const float4*)&b1[4 * hl];
    float v0 = acc0 / srh + bb.x;
    float v1 = acc1 / srh + bb.y;
    float v2 = acc2 / srh + bb.z;
    float v3 = acc3 / srh + bb.w;
    v0 = v0 > 0.f ? v0 : (__expf(v0) - 1.f);
    v1 = v1 > 0.f ? v1 : (__expf(v1) - 1.f);
    v2 = v2 > 0.f ? v2 : (__expf(v2) - 1.f);
    v3 = v3 > 0.f ? v3 : (__expf(v3) - 1.f);
    *(float4*)&z[(size_t)node * F1 + 4 * hl] = make_float4(v0, v1, v2, v3);
}

// ============ fused layer-2 GAT + log_softmax (fp16 gather) ============
__global__ __launch_bounds__(256) void k_gat2(
    const int* __restrict__ row_off, const int* __restrict__ csr,
    const float* __restrict__ as2, const float* __restrict__ ad2,
    const unsigned short* __restrict__ h2h, const float* __restrict__ b2,
    float* __restrict__ y, int n)
{
    int nb = threadIdx.x >> 5;
    int hl = threadIdx.x & 31;
    int node = blockIdx.x * 8 + nb;
    if (node >= n) return;
    __shared__ int   s_src[8][32];   // 1 KB
    __shared__ float s_p[8][32];     // 1 KB
    int* ssrc = s_src[nb];
    float* sp = s_p[nb];

    float addv = ad2[node];
    int beg = row_off[node], end = row_off[node + 1];
    float mr = -1e30f, sr = 0.f, acc = 0.f;

    for (int c = beg; c < end; c += 32) {
        int cnt = min(32, end - c);
        bool has = hl < cnt;
        float sc = -1e30f;
        if (has) {
            int sA = csr[c + hl];
            ssrc[hl] = sA;
            float v = as2[sA] + addv;
            sc = v > 0.f ? v : NEG * v;
        }
        float lm = sc;
        #pragma unroll
        for (int o = 16; o; o >>= 1) lm = fmaxf(lm, __shfl_xor(lm, o));
        float nm = fmaxf(mr, lm);
        float r = __expf(mr - nm);
        acc *= r; sr *= r;
        float ls = 0.f;
        if (has) {
            float p = __expf(sc - nm);
            sp[hl] = p;
            ls = p;
        }
        #pragma unroll
        for (int o = 16; o; o >>= 1) ls += __shfl_xor(ls, o);
        sr += ls;
        __threadfence_block();
        int nfull = cnt & ~3;
        for (int jj = 0; jj < nfull; jj += 4) {
            int s0 = ssrc[jj], s1 = ssrc[jj + 1];
            int s2 = ssrc[jj + 2], s3 = ssrc[jj + 3];
            float p0 = sp[jj], p1 = sp[jj + 1];
            float p2 = sp[jj + 2], p3 = sp[jj + 3];
            unsigned short u0 = h2h[(size_t)s0 * 32 + hl];
            unsigned short u1 = h2h[(size_t)s1 * 32 + hl];
            unsigned short u2 = h2h[(size_t)s2 * 32 + hl];
            unsigned short u3 = h2h[(size_t)s3 * 32 + hl];
            acc = fmaf(p0, h2f(u0), acc);
            acc = fmaf(p1, h2f(u1), acc);
            acc = fmaf(p2, h2f(u2), acc);
            acc = fmaf(p3, h2f(u3), acc);
        }
        for (int j = nfull; j < cnt; ++j) {
            acc = fmaf(sp[j], h2f(h2h[(size_t)ssrc[j] * 32 + hl]), acc);
        }
        mr = nm;
    }
    float v = acc / sr + b2[hl];
    float m = v;
    #pragma unroll
    for (int o = 16; o; o >>= 1) m = fmaxf(m, __shfl_xor(m, o));
    float ex = __expf(v - m), ss = ex;
    #pragma unroll
    for (int o = 16; o; o >>= 1) ss += __shfl_xor(ss, o);
    y[(size_t)node * OUT_C + hl] = v - m - logf(ss);
}

extern "C" void kernel_launch(void* const* d_in, const int* in_sizes, int n_in,
                              void* d_out, int out_size, void* d_ws, size_t ws_size,
                              hipStream_t stream) {
    const float* x    = (const float*)d_in[0];
    const int*   ei   = (const int*)d_in[1];
    const float* W1   = (const float*)d_in[2];
    const float* as1w = (const float*)d_in[3];
    const float* ad1w = (const float*)d_in[4];
    const float* b1   = (const float*)d_in[5];
    const float* W2   = (const float*)d_in[6];
    const float* as2w = (const float*)d_in[7];
    const float* ad2w = (const float*)d_in[8];
    const float* b2   = (const float*)d_in[9];
    float* out = (float*)d_out;

    int n  = in_sizes[0] / IN_C;
    int E_ = in_sizes[1] / 2;
    int EE = E_ + n;

    int NB = (n + (1 << SH) - 1) >> SH;        // buckets (<=512 for n<=131072)
    int NC = (EE + CHA - 1) / CHA;             // chunks
    int M  = NB * NC;
    int NBLK = (M + SCB - 1) / SCB;            // scan blocks (<=256)

    char* w = (char*)d_ws;
    size_t off = 0;
    auto take = [&](size_t elems) { void* p = w + off; off += ((elems * 4 + 255) & ~(size_t)255); return p; };
    int* bmat      = (int*)take((size_t)M);
    int* bsums     = (int*)take(256);
    unsigned* recs = (unsigned*)take((size_t)EE);
    int* row_off   = (int*)take((size_t)n + 1);
    int* csr       = (int*)take((size_t)EE);
    float* as1     = (float*)take((size_t)n * 4);
    float* ad1     = (float*)take((size_t)n * 4);
    unsigned short* h1h = (unsigned short*)take((size_t)n * 64);  // n*128 fp16
    float* z       = (float*)take((size_t)n * 128);
    unsigned short* h2h = (unsigned short*)take((size_t)n * 16);  // n*32 fp16
    float* as2     = (float*)take((size_t)n);
    float* ad2     = (float*)take((size_t)n);

    // CSR build: bucketed counting sort, no global atomics, parallel scan
    k_bhist   <<<NC, 256, 0, stream>>>(ei, bmat, E_, n, NB, NC);
    k_scanA   <<<NBLK, 256, 0, stream>>>(bmat, bsums, M);
    k_scanB   <<<1, 256, 0, stream>>>(bsums, NBLK);
    k_scanC   <<<(M + 255) / 256, 256, 0, stream>>>(bmat, bsums, M);
    k_bscatter<<<NC, 256, 0, stream>>>(ei, bmat, recs, E_, n, NB, NC);
    k_bfill   <<<NB, 256, 0, stream>>>(recs, bmat, row_off, csr, n, NB, NC, EE);

    // layer 1
    int nt = (n + 63) / 64;
    k_gemm1<<<nt * 2, 256, 0, stream>>>(x, W1, as1w, ad1w, h1h, as1, ad1, n);
    int gG = (n + 7) / 8;
    k_gat1<<<gG, 256, 0, stream>>>(row_off, csr, as1, ad1, h1h, b1, z, n);

    // layer 2
    k_gemm2<<<nt, 256, 0, stream>>>(z, W2, as2w, ad2w, h2h, as2, ad2, n);
    k_gat2<<<gG, 256, 0, stream>>>(row_off, csr, as2, ad2, h2h, b2, out, n);
}